// Round 4
// baseline (1013.735 us; speedup 1.0000x reference)
//
#include <hip/hip_runtime.h>

// ---------------- constants ----------------
#define B_   16
#define T_   512
#define M_   8
#define S_   32
#define D_   256
#define H_   4
#define HD_  64
#define TM_  4096      // T*M
#define NKT  40        // M+S
#define NKS  4128      // T*M+S

typedef unsigned short u16;

// ---------------- bf16 helpers ----------------
__device__ __forceinline__ u16 f2b(float f) {
    union { float f; unsigned u; } v; v.f = f;
    unsigned r = v.u + 0x7FFF + ((v.u >> 16) & 1);   // RNE
    return (u16)(r >> 16);
}
__device__ __forceinline__ float blo(unsigned u) {
    union { unsigned i; float f; } v; v.i = u << 16; return v.f;
}
__device__ __forceinline__ float bhi(unsigned u) {
    union { unsigned i; float f; } v; v.i = u & 0xFFFF0000u; return v.f;
}
__device__ __forceinline__ float b2f(u16 u) {
    union { unsigned i; float f; } v; v.i = ((unsigned)u) << 16; return v.f;
}
__device__ __forceinline__ float dot8(uint4 a, uint4 b) {
    return blo(a.x)*blo(b.x) + bhi(a.x)*bhi(b.x)
         + blo(a.y)*blo(b.y) + bhi(a.y)*bhi(b.y)
         + blo(a.z)*blo(b.z) + bhi(a.z)*bhi(b.z)
         + blo(a.w)*blo(b.w) + bhi(a.w)*bhi(b.w);
}
__device__ __forceinline__ unsigned pack2(float lo, float hi) {
    return (unsigned)f2b(lo) | ((unsigned)f2b(hi) << 16);
}

// ---------------- VALU GEMM: Y[r][c] = X[r]·W[c] + bias[c], Y FLOAT32 ----------
// X: [R][256] f32.  W: [256][256] f32, row c = weights of output feature c.
// grid = (4, R/64), block = 256. Tile 64x64, K-chunks of 64. 16 outputs/thread.
__global__ __launch_bounds__(256) void k_gemm_v_f32(const float* __restrict__ X,
                                                    const float* __restrict__ W,
                                                    const float* __restrict__ bias,
                                                    u16* __restrict__ Ybf,
                                                    float* __restrict__ Yf)
{
    __shared__ float sX[64][68];
    __shared__ float sW[64][68];
    const int tid = threadIdx.x;
    const int c0  = blockIdx.x * 64;
    const size_t r0 = (size_t)blockIdx.y * 64;
    const int tr = tid >> 4, tc = tid & 15;          // thread tile: rows tr*4.., cols tc*4..

    float acc[4][4] = {{0,0,0,0},{0,0,0,0},{0,0,0,0},{0,0,0,0}};

    for (int kc = 0; kc < 4; ++kc) {
        if (kc) __syncthreads();
#pragma unroll
        for (int i = 0; i < 4; ++i) {
            const int f4 = tid + i * 256;            // 0..1023
            const int row = f4 >> 4, seg = f4 & 15;  // 64 rows x 16 float4 segs
            *(float4*)&sX[row][seg * 4] =
                *(const float4*)(X + (r0 + row) * 256 + kc * 64 + seg * 4);
            *(float4*)&sW[row][seg * 4] =
                *(const float4*)(W + (size_t)(c0 + row) * 256 + kc * 64 + seg * 4);
        }
        __syncthreads();
        for (int kk = 0; kk < 64; ++kk) {
            float xv[4], wv[4];
#pragma unroll
            for (int i = 0; i < 4; ++i) xv[i] = sX[tr * 4 + i][kk];
#pragma unroll
            for (int j = 0; j < 4; ++j) wv[j] = sW[tc * 4 + j][kk];
#pragma unroll
            for (int i = 0; i < 4; ++i)
#pragma unroll
                for (int j = 0; j < 4; ++j) acc[i][j] += xv[i] * wv[j];
        }
    }

#pragma unroll
    for (int j = 0; j < 4; ++j) {
        const int col = c0 + tc * 4 + j;
        const float bv = bias[col];
#pragma unroll
        for (int i = 0; i < 4; ++i) {
            const size_t row = r0 + tr * 4 + i;
            const float y = acc[i][j] + bv;
            if (Ybf) Ybf[row * 256 + col] = f2b(y);   // bf16 ws intermediate
            else     Yf [row * 256 + col] = y;        // f32 final output
        }
    }
}

// Same, X is bf16 (ws intermediates), Y = f32 final output.
__global__ __launch_bounds__(256) void k_gemm_v_bf(const u16* __restrict__ X,
                                                   const float* __restrict__ W,
                                                   const float* __restrict__ bias,
                                                   float* __restrict__ Y)
{
    __shared__ float sX[64][68];
    __shared__ float sW[64][68];
    const int tid = threadIdx.x;
    const int c0  = blockIdx.x * 64;
    const size_t r0 = (size_t)blockIdx.y * 64;
    const int tr = tid >> 4, tc = tid & 15;

    float acc[4][4] = {{0,0,0,0},{0,0,0,0},{0,0,0,0},{0,0,0,0}};

    for (int kc = 0; kc < 4; ++kc) {
        if (kc) __syncthreads();
#pragma unroll
        for (int i = 0; i < 4; ++i) {
            const int f4 = tid + i * 256;
            const int row = f4 >> 4, seg = f4 & 15;
            const uint2 u = *(const uint2*)(X + (r0 + row) * 256 + kc * 64 + seg * 4);
            float4 xf; xf.x = blo(u.x); xf.y = bhi(u.x); xf.z = blo(u.y); xf.w = bhi(u.y);
            *(float4*)&sX[row][seg * 4] = xf;
            *(float4*)&sW[row][seg * 4] =
                *(const float4*)(W + (size_t)(c0 + row) * 256 + kc * 64 + seg * 4);
        }
        __syncthreads();
        for (int kk = 0; kk < 64; ++kk) {
            float xv[4], wv[4];
#pragma unroll
            for (int i = 0; i < 4; ++i) xv[i] = sX[tr * 4 + i][kk];
#pragma unroll
            for (int j = 0; j < 4; ++j) wv[j] = sW[tc * 4 + j][kk];
#pragma unroll
            for (int i = 0; i < 4; ++i)
#pragma unroll
                for (int j = 0; j < 4; ++j) acc[i][j] += xv[i] * wv[j];
        }
    }

#pragma unroll
    for (int j = 0; j < 4; ++j) {
        const int col = c0 + tc * 4 + j;
        const float bv = bias[col];
#pragma unroll
        for (int i = 0; i < 4; ++i) {
            const size_t row = r0 + tr * 4 + i;
            Y[row * 256 + col] = acc[i][j] + bv;
        }
    }
}

// ---------------- temporal attention: one block per (t,b) ----------------
// 32 query rows (h,m), 40 key cols (8 temporal masked + 32 static).
#define STP 264   // padded LDS row stride (u16)
__global__ __launch_bounds__(256) void k_attn_t(
    const u16* __restrict__ Qt, const u16* __restrict__ Kt, const u16* __restrict__ Vt,
    const u16* __restrict__ Ks, const u16* __restrict__ Vs,
    const int* __restrict__ maskT, const int* __restrict__ maskS,
    float* __restrict__ tw, u16* __restrict__ qkvt)
{
    const int t = blockIdx.x, b = blockIdx.y;
    __shared__ __align__(16) u16 sQ[8 * STP], sK[8 * STP], sV[8 * STP];
    __shared__ __align__(16) u16 sKs[32 * STP], sVs[32 * STP];
    __shared__ float sS[32][NKT];
    __shared__ int smT[8], smS[32];
    const int tid = threadIdx.x;
    const size_t baseT = ((size_t)b * T_ + t) * (M_ * D_);

    {   // stage Q/K/V (8x256) and Ks/Vs (32x256), padded rows of 33 uint4
        const uint4* gq = (const uint4*)(Qt + baseT);
        const uint4* gk = (const uint4*)(Kt + baseT);
        const uint4* gv = (const uint4*)(Vt + baseT);
        const int r1 = tid >> 5, s1 = tid & 31, d1 = r1 * 33 + s1;
        ((uint4*)sQ)[d1] = gq[tid];
        ((uint4*)sK)[d1] = gk[tid];
        ((uint4*)sV)[d1] = gv[tid];
        const uint4* gks = (const uint4*)(Ks + (size_t)b * (S_ * D_));
        const uint4* gvs = (const uint4*)(Vs + (size_t)b * (S_ * D_));
#pragma unroll
        for (int i = 0; i < 4; ++i) {
            const int fl = tid + i * 256;
            const int r2 = fl >> 5, s2 = fl & 31, d2 = r2 * 33 + s2;
            ((uint4*)sKs)[d2] = gks[fl];
            ((uint4*)sVs)[d2] = gvs[fl];
        }
        if (tid < 8)  smT[tid] = maskT[((size_t)b * T_ + t) * M_ + tid];
        if (tid < 32) smS[tid] = maskS[b * S_ + tid];
    }
    __syncthreads();

    const int row = tid >> 3;          // 0..31
    const int h = row >> 3, m = row & 7;
    const int j = tid & 7;             // 8 lanes per row

    const uint4* qp = (const uint4*)(sQ + m * STP + h * HD_);
    uint4 qr[8];
#pragma unroll
    for (int i8 = 0; i8 < 8; ++i8) qr[i8] = qp[i8];

    float sc[5];
#pragma unroll
    for (int ci = 0; ci < 5; ++ci) {
        const int c = j + 8 * ci;      // 0..39
        const uint4* kp = (c < 8) ? (const uint4*)(sK  +  c      * STP + h * HD_)
                                  : (const uint4*)(sKs + (c - 8) * STP + h * HD_);
        float acc = 0.f;
#pragma unroll
        for (int i8 = 0; i8 < 8; ++i8) acc += dot8(qr[i8], kp[i8]);
        const int valid = (c < 8) ? smT[c] : smS[c - 8];
        sc[ci] = valid ? acc * 0.125f : -1e30f;
    }

    // softmax over the row's 40 cols (8 lanes x 5 each)
    float mx = fmaxf(fmaxf(fmaxf(sc[0], sc[1]), fmaxf(sc[2], sc[3])), sc[4]);
    mx = fmaxf(mx, __shfl_xor(mx, 1));
    mx = fmaxf(mx, __shfl_xor(mx, 2));
    mx = fmaxf(mx, __shfl_xor(mx, 4));
    float sum = 0.f;
#pragma unroll
    for (int ci = 0; ci < 5; ++ci) { sc[ci] = __expf(sc[ci] - mx); sum += sc[ci]; }
    sum += __shfl_xor(sum, 1);
    sum += __shfl_xor(sum, 2);
    sum += __shfl_xor(sum, 4);
    const float inv = 1.0f / sum;

    const size_t twbase = ((((size_t)b * H_ + h) * T_ + t) * M_ + m) * NKT;
#pragma unroll
    for (int ci = 0; ci < 5; ++ci) {
        const int c = j + 8 * ci;
        const float w = sc[ci] * inv;
        sS[row][c] = w;
        tw[twbase + c] = w;            // f32 output
    }
    __syncthreads();

    // PV: this thread owns dims d = j*8 .. j*8+7 of row (h,m)
    float acc[8] = {0,0,0,0,0,0,0,0};
    for (int c = 0; c < NKT; ++c) {
        const float w = sS[row][c];
        const uint4* vp = (c < 8) ? (const uint4*)(sV  +  c      * STP + h * HD_)
                                  : (const uint4*)(sVs + (c - 8) * STP + h * HD_);
        const uint4 v4 = vp[j];
        acc[0] += w * blo(v4.x); acc[1] += w * bhi(v4.x);
        acc[2] += w * blo(v4.y); acc[3] += w * bhi(v4.y);
        acc[4] += w * blo(v4.z); acc[5] += w * bhi(v4.z);
        acc[6] += w * blo(v4.w); acc[7] += w * bhi(v4.w);
    }
    uint4 o;
    o.x = pack2(acc[0], acc[1]); o.y = pack2(acc[2], acc[3]);
    o.z = pack2(acc[4], acc[5]); o.w = pack2(acc[6], acc[7]);
    *(uint4*)(qkvt + baseT + m * D_ + h * HD_ + j * 8) = o;
}

// ---------------- static branch: raw masked scores ----------------
// grid = (33, H, B); chunks 0..31 = 128 temporal keys, chunk 32 = 32 static keys.
#define SKP 72
__global__ __launch_bounds__(256) void k_attn_s_scores(
    const u16* __restrict__ Qs, const u16* __restrict__ Kt, const u16* __restrict__ Ks,
    const int* __restrict__ maskT, const int* __restrict__ maskS,
    float* __restrict__ raw)
{
    const int ch = blockIdx.x;
    const int h = blockIdx.y, b = blockIdx.z;
    const int nk = (ch < 32) ? 128 : 32;
    const int k0 = ch * 128;
    __shared__ __align__(16) u16 sK[128 * SKP];
    __shared__ __align__(16) u16 sQ[32 * SKP];
    __shared__ int sM[128];
    const int tid = threadIdx.x;

    {   const int q = tid >> 3, part = tid & 7;
        ((uint4*)sQ)[q * 9 + part] =
            *(const uint4*)(Qs + ((size_t)b * S_ + q) * D_ + h * HD_ + part * 8);
    }
#pragma unroll
    for (int i = 0; i < 4; ++i) {
        const int fl = tid + i * 256;
        const int key = fl >> 3, part = fl & 7;
        if (key < nk) {
            const u16* src = (ch < 32)
                ? (Kt + ((size_t)b * TM_ + k0 + key) * D_ + h * HD_ + part * 8)
                : (Ks + ((size_t)b * S_  +      key) * D_ + h * HD_ + part * 8);
            ((uint4*)sK)[key * 9 + part] = *(const uint4*)src;
        }
    }
    if (tid < nk) sM[tid] = (ch < 32) ? maskT[(size_t)b * TM_ + k0 + tid]
                                      : maskS[b * S_ + tid];
    __syncthreads();

    const int q = tid >> 3, j = tid & 7;
    const uint4* qp = (const uint4*)(sQ + q * SKP);
    uint4 qr[8];
#pragma unroll
    for (int i8 = 0; i8 < 8; ++i8) qr[i8] = qp[i8];

    float* rowp = raw + (((size_t)b * H_ + h) * S_ + q) * NKS + k0;
    for (int ii = 0; ii < 16; ++ii) {
        const int kk = j + 8 * ii;
        if (kk >= nk) break;
        const uint4* kp = (const uint4*)(sK + kk * SKP);
        float acc = 0.f;
#pragma unroll
        for (int i8 = 0; i8 < 8; ++i8) acc += dot8(qr[i8], kp[i8]);
        rowp[kk] = acc * 0.125f + (sM[kk] ? 0.f : -1e30f);
    }
}

// ---------------- static branch: row softmax (in-place f32 + f32 sw out) --------
// grid = (S, H, B), one block per row of 4128.
__global__ __launch_bounds__(256) void k_attn_s_softmax(
    float* __restrict__ raw, float* __restrict__ sw)
{
    const int q = blockIdx.x, h = blockIdx.y, b = blockIdx.z;
    __shared__ float sRow[NKS];
    __shared__ float red[8];
    const int tid = threadIdx.x;
    const size_t base = (((size_t)b * H_ + h) * S_ + q) * NKS;

    float mx = -1e30f;
    for (int i = tid; i < NKS; i += 256) {
        const float v = raw[base + i];
        sRow[i] = v;
        mx = fmaxf(mx, v);
    }
    for (int o = 32; o; o >>= 1) mx = fmaxf(mx, __shfl_xor(mx, o));
    if ((tid & 63) == 0) red[tid >> 6] = mx;
    __syncthreads();
    mx = fmaxf(fmaxf(red[0], red[1]), fmaxf(red[2], red[3]));

    float sum = 0.f;
    for (int i = tid; i < NKS; i += 256) {
        const float e = __expf(sRow[i] - mx);
        sRow[i] = e;
        sum += e;
    }
    for (int o = 32; o; o >>= 1) sum += __shfl_xor(sum, o);
    if ((tid & 63) == 0) red[4 + (tid >> 6)] = sum;
    __syncthreads();
    sum = (red[4] + red[5]) + (red[6] + red[7]);
    const float inv = 1.0f / sum;

    for (int i = tid; i < NKS; i += 256) {
        const float w = sRow[i] * inv;
        raw[base + i] = w;          // normalized weights for PV kernel
        sw[base + i]  = w;          // f32 harness output
    }
}

// ---------------- static branch: PV ----------------
// grid = (2, H, B): 16 q-rows per block; thread = (d = tid&63, qg = tid>>6), 4 q each.
__global__ __launch_bounds__(256) void k_attn_s_pv(
    const float* __restrict__ w, const u16* __restrict__ Vt, const u16* __restrict__ Vs,
    u16* __restrict__ qkvs)
{
    const int qh = blockIdx.x, h = blockIdx.y, b = blockIdx.z;
    __shared__ float sWT[128][20];                 // [kk][q], padded
    __shared__ __align__(16) u16 sV[128 * 64];
    const int tid = threadIdx.x;
    const int d = tid & 63, qg = tid >> 6;
    float a0 = 0.f, a1 = 0.f, a2 = 0.f, a3 = 0.f;

    for (int ch = 0; ch < 33; ++ch) {
        const int nk = (ch < 32) ? 128 : 32;
        const int k0 = ch * 128;
        __syncthreads();
#pragma unroll
        for (int i = 0; i < 8; ++i) {
            const int fl = tid + i * 256;
            const int qq = fl >> 7, kk = fl & 127;
            sWT[kk][qq] = (kk < nk)
                ? w[(((size_t)b * H_ + h) * S_ + qh * 16 + qq) * NKS + k0 + kk] : 0.f;
        }
#pragma unroll
        for (int i = 0; i < 4; ++i) {
            const int fl = tid + i * 256;
            const int key = fl >> 3, part = fl & 7;
            if (key < nk) {
                const u16* src = (ch < 32)
                    ? (Vt + ((size_t)b * TM_ + k0 + key) * D_ + h * HD_ + part * 8)
                    : (Vs + ((size_t)b * S_  +      key) * D_ + h * HD_ + part * 8);
                ((uint4*)sV)[fl] = *(const uint4*)src;
            }
        }
        __syncthreads();
        for (int kk = 0; kk < nk; ++kk) {
            const float v = b2f(sV[kk * 64 + d]);
            const float4 w4 = *(const float4*)&sWT[kk][qg * 4];
            a0 += w4.x * v; a1 += w4.y * v; a2 += w4.z * v; a3 += w4.w * v;
        }
    }
    const size_t ob = ((size_t)b * S_ + qh * 16 + qg * 4) * D_ + h * HD_ + d;
    qkvs[ob         ] = f2b(a0);
    qkvs[ob +     D_] = f2b(a1);
    qkvs[ob + 2 * D_] = f2b(a2);
    qkvs[ob + 3 * D_] = f2b(a3);
}

// ---------------- launch ----------------
extern "C" void kernel_launch(void* const* d_in, const int* in_sizes, int n_in,
                              void* d_out, int out_size, void* d_ws, size_t ws_size,
                              hipStream_t stream)
{
    const float* q_t = (const float*)d_in[0];
    const float* q_s = (const float*)d_in[1];
    const float* k_t = (const float*)d_in[2];
    const float* v_t = (const float*)d_in[3];
    const float* k_s = (const float*)d_in[4];
    const float* v_s = (const float*)d_in[5];
    const float* q_w = (const float*)d_in[6];
    const float* q_b = (const float*)d_in[7];
    const float* k_w = (const float*)d_in[8];
    const float* k_b = (const float*)d_in[9];
    const float* v_w = (const float*)d_in[10];
    const float* v_b = (const float*)d_in[11];
    const float* o_w = (const float*)d_in[12];
    const float* o_b = (const float*)d_in[13];
    const int* maskT = (const int*)d_in[14];
    // d_in[15] = mask_fcst: unused by the reference
    const int* maskS = (const int*)d_in[16];
    float* out = (float*)d_out;       // FLOAT32 outputs (reference output dtype)

    char* ws = (char*)d_ws;
    u16*   Kt   = (u16*)(ws + 0);
    u16*   Vt   = (u16*)(ws + 33554432);
    u16*   QKVt = (u16*)(ws + 67108864);
    u16*   Qs   = (u16*)(ws + 100663296);
    u16*   Ks   = (u16*)(ws + 100925440);
    u16*   Vs   = (u16*)(ws + 101187584);
    u16*   QKVs = (u16*)(ws + 101449728);
    u16*   Qt   = (u16*)(ws + 101711872);
    float* raw  = (float*)(ws + 101711872);  // aliases Qt (dead before scores run)
    if (ws_size < 135528448) return;         // required workspace

    float* out_t = out;                 // [B,T,M,D]
    float* out_s = out + 16777216;      // [B,S,D]
    float* tw    = out + 16908288;      // [B,H,T,M,40]
    float* sw    = out + 27394048;      // [B,H,S,4128]

    const dim3 blk(256);
    k_gemm_v_f32<<<dim3(4, 1024), blk, 0, stream>>>(q_t, q_w, q_b, Qt, nullptr);
    k_gemm_v_f32<<<dim3(4, 1024), blk, 0, stream>>>(k_t, k_w, k_b, Kt, nullptr);
    k_gemm_v_f32<<<dim3(4, 1024), blk, 0, stream>>>(v_t, v_w, v_b, Vt, nullptr);
    k_gemm_v_f32<<<dim3(4, 8),    blk, 0, stream>>>(q_s, q_w, q_b, Qs, nullptr);
    k_gemm_v_f32<<<dim3(4, 8),    blk, 0, stream>>>(k_s, k_w, k_b, Ks, nullptr);
    k_gemm_v_f32<<<dim3(4, 8),    blk, 0, stream>>>(v_s, v_w, v_b, Vs, nullptr);

    k_attn_t<<<dim3(512, 16), blk, 0, stream>>>(Qt, Kt, Vt, Ks, Vs, maskT, maskS, tw, QKVt);

    k_attn_s_scores<<<dim3(33, 4, 16), blk, 0, stream>>>(Qs, Kt, Ks, maskT, maskS, raw);
    k_attn_s_softmax<<<dim3(32, 4, 16), blk, 0, stream>>>(raw, sw);
    k_attn_s_pv<<<dim3(2, 4, 16), blk, 0, stream>>>(raw, Vt, Vs, QKVs);

    k_gemm_v_bf<<<dim3(4, 1024), blk, 0, stream>>>(QKVt, o_w, o_b, out_t);
    k_gemm_v_bf<<<dim3(4, 8),    blk, 0, stream>>>(QKVs, o_w, o_b, out_s);
}

// Round 5
// 513.491 us; speedup vs baseline: 1.9742x; 1.9742x over previous
//
#include <hip/hip_runtime.h>

// ---------------- constants ----------------
#define B_   16
#define T_   512
#define M_   8
#define S_   32
#define D_   256
#define H_   4
#define HD_  64
#define TM_  4096      // T*M
#define NKT  40        // M+S
#define NKS  4128      // T*M+S

typedef unsigned short u16;
typedef __attribute__((ext_vector_type(8))) short bf16x8;
typedef __attribute__((ext_vector_type(4))) float f32x4;

// ---------------- bf16 helpers ----------------
__device__ __forceinline__ u16 f2b(float f) {
    union { float f; unsigned u; } v; v.f = f;
    unsigned r = v.u + 0x7FFF + ((v.u >> 16) & 1);   // RNE
    return (u16)(r >> 16);
}
__device__ __forceinline__ float blo(unsigned u) {
    union { unsigned i; float f; } v; v.i = u << 16; return v.f;
}
__device__ __forceinline__ float bhi(unsigned u) {
    union { unsigned i; float f; } v; v.i = u & 0xFFFF0000u; return v.f;
}
__device__ __forceinline__ float b2f(u16 u) {
    union { unsigned i; float f; } v; v.i = ((unsigned)u) << 16; return v.f;
}
__device__ __forceinline__ float dot8(uint4 a, uint4 b) {
    return blo(a.x)*blo(b.x) + bhi(a.x)*bhi(b.x)
         + blo(a.y)*blo(b.y) + bhi(a.y)*bhi(b.y)
         + blo(a.z)*blo(b.z) + bhi(a.z)*bhi(b.z)
         + blo(a.w)*blo(b.w) + bhi(a.w)*bhi(b.w);
}
__device__ __forceinline__ unsigned pack2(float lo, float hi) {
    return (unsigned)f2b(lo) | ((unsigned)f2b(hi) << 16);
}
__device__ __forceinline__ uint4 cvt8(float4 a, float4 b) {
    uint4 r;
    r.x = pack2(a.x, a.y); r.y = pack2(a.z, a.w);
    r.z = pack2(b.x, b.y); r.w = pack2(b.z, b.w);
    return r;
}

// ---------------- MFMA GEMM: Y[r][c] = X[r]·W[c] + bias[c] ----------------
// Tile: 64 rows x 256 cols (whole N) per block, BK=32, 4 waves (wave w = cols
// w*64..w*64+63). All-linear LDS: staging writes are contiguous 16B slots per
// instruction; each wave's fragment read covers a contiguous 1KB block ->
// bank-conflict-free with zero padding.
// XBF: X is bf16 (ws intermediate) vs f32. OUTF32: write f32 (d_out) vs bf16 (ws).
template<int XBF, int OUTF32>
__global__ __launch_bounds__(256) void k_gemm_m(const void* __restrict__ Xv,
                                                const float* __restrict__ W,
                                                const float* __restrict__ bias,
                                                void* __restrict__ Yv)
{
    __shared__ __align__(16) u16 sA[64 * 32];
    __shared__ __align__(16) u16 sB[256 * 32];
    const int tid = threadIdx.x;
    const size_t r0 = (size_t)blockIdx.x * 64;
    const int wave = tid >> 6, lane = tid & 63;
    const int rbase = lane & 15, kseg = (lane >> 4) * 8;

    f32x4 acc[4][4];
#pragma unroll
    for (int i = 0; i < 4; ++i)
#pragma unroll
        for (int j = 0; j < 4; ++j) acc[i][j] = (f32x4){0, 0, 0, 0};

    const int arow = tid >> 2, aseg = tid & 3;     // A staging: 64 rows x 4 segs

    for (int k0 = 0; k0 < 256; k0 += 32) {
        // -- load next tile into regs (before barrier; hides latency) --
        uint4 aW;
        if (XBF) {
            aW = *(const uint4*)((const u16*)Xv + (r0 + arow) * 256 + k0 + aseg * 8);
        } else {
            const float* gA = (const float*)Xv + (r0 + arow) * 256 + k0 + aseg * 8;
            aW = cvt8(*(const float4*)gA, *(const float4*)(gA + 4));
        }
        uint4 bW[4];
#pragma unroll
        for (int i = 0; i < 4; ++i) {
            const int s = i * 256 + tid;           // 16B slot id in B tile
            const float* gB = W + (size_t)(s >> 2) * 256 + k0 + (s & 3) * 8;
            bW[i] = cvt8(*(const float4*)gB, *(const float4*)(gB + 4));
        }
        if (k0) __syncthreads();                   // protect prior reads
        *(uint4*)(sA + tid * 8) = aW;              // slot t  (row-major 64x32)
#pragma unroll
        for (int i = 0; i < 4; ++i)
            *(uint4*)(sB + (i * 256 + tid) * 8) = bW[i];   // contiguous per inst
        __syncthreads();

        bf16x8 a[4], b[4];
#pragma unroll
        for (int f = 0; f < 4; ++f)
            a[f] = *(const bf16x8*)(sA + (f * 16 + rbase) * 32 + kseg);
#pragma unroll
        for (int f = 0; f < 4; ++f)
            b[f] = *(const bf16x8*)(sB + (wave * 64 + f * 16 + rbase) * 32 + kseg);
#pragma unroll
        for (int rf = 0; rf < 4; ++rf)
#pragma unroll
            for (int cf = 0; cf < 4; ++cf)
                acc[rf][cf] = __builtin_amdgcn_mfma_f32_16x16x32_bf16(
                    a[rf], b[cf], acc[rf][cf], 0, 0, 0);
    }

    // C/D mapping (verified m89 + round2/3 bit-identity): col=lane&15, row=(lane>>4)*4+reg
    const int orow = (lane >> 4) * 4, ocol = lane & 15;
#pragma unroll
    for (int cf = 0; cf < 4; ++cf) {
        const int col = wave * 64 + cf * 16 + ocol;
        const float bv = bias[col];
#pragma unroll
        for (int rf = 0; rf < 4; ++rf)
#pragma unroll
            for (int r = 0; r < 4; ++r) {
                const size_t row = r0 + rf * 16 + orow + r;
                const float y = acc[rf][cf][r] + bv;
                if (OUTF32) ((float*)Yv)[row * 256 + col] = y;
                else        ((u16*) Yv)[row * 256 + col] = f2b(y);
            }
    }
}

// ---------------- temporal attention: one block per (t,b) ----------------
// 32 query rows (h,m), 40 key cols (8 temporal masked + 32 static).
#define STP 264   // padded LDS row stride (u16)
__global__ __launch_bounds__(256) void k_attn_t(
    const u16* __restrict__ Qt, const u16* __restrict__ Kt, const u16* __restrict__ Vt,
    const u16* __restrict__ Ks, const u16* __restrict__ Vs,
    const int* __restrict__ maskT, const int* __restrict__ maskS,
    float* __restrict__ tw, u16* __restrict__ qkvt)
{
    const int t = blockIdx.x, b = blockIdx.y;
    __shared__ __align__(16) u16 sQ[8 * STP], sK[8 * STP], sV[8 * STP];
    __shared__ __align__(16) u16 sKs[32 * STP], sVs[32 * STP];
    __shared__ float sS[32][NKT];
    __shared__ int smT[8], smS[32];
    const int tid = threadIdx.x;
    const size_t baseT = ((size_t)b * T_ + t) * (M_ * D_);

    {   // stage Q/K/V (8x256) and Ks/Vs (32x256), padded rows of 33 uint4
        const uint4* gq = (const uint4*)(Qt + baseT);
        const uint4* gk = (const uint4*)(Kt + baseT);
        const uint4* gv = (const uint4*)(Vt + baseT);
        const int r1 = tid >> 5, s1 = tid & 31, d1 = r1 * 33 + s1;
        ((uint4*)sQ)[d1] = gq[tid];
        ((uint4*)sK)[d1] = gk[tid];
        ((uint4*)sV)[d1] = gv[tid];
        const uint4* gks = (const uint4*)(Ks + (size_t)b * (S_ * D_));
        const uint4* gvs = (const uint4*)(Vs + (size_t)b * (S_ * D_));
#pragma unroll
        for (int i = 0; i < 4; ++i) {
            const int fl = tid + i * 256;
            const int r2 = fl >> 5, s2 = fl & 31, d2 = r2 * 33 + s2;
            ((uint4*)sKs)[d2] = gks[fl];
            ((uint4*)sVs)[d2] = gvs[fl];
        }
        if (tid < 8)  smT[tid] = maskT[((size_t)b * T_ + t) * M_ + tid];
        if (tid < 32) smS[tid] = maskS[b * S_ + tid];
    }
    __syncthreads();

    const int row = tid >> 3;          // 0..31
    const int h = row >> 3, m = row & 7;
    const int j = tid & 7;             // 8 lanes per row

    const uint4* qp = (const uint4*)(sQ + m * STP + h * HD_);
    uint4 qr[8];
#pragma unroll
    for (int i8 = 0; i8 < 8; ++i8) qr[i8] = qp[i8];

    float sc[5];
#pragma unroll
    for (int ci = 0; ci < 5; ++ci) {
        const int c = j + 8 * ci;      // 0..39
        const uint4* kp = (c < 8) ? (const uint4*)(sK  +  c      * STP + h * HD_)
                                  : (const uint4*)(sKs + (c - 8) * STP + h * HD_);
        float acc = 0.f;
#pragma unroll
        for (int i8 = 0; i8 < 8; ++i8) acc += dot8(qr[i8], kp[i8]);
        const int valid = (c < 8) ? smT[c] : smS[c - 8];
        sc[ci] = valid ? acc * 0.125f : -1e30f;
    }

    // softmax over the row's 40 cols (8 lanes x 5 each)
    float mx = fmaxf(fmaxf(fmaxf(sc[0], sc[1]), fmaxf(sc[2], sc[3])), sc[4]);
    mx = fmaxf(mx, __shfl_xor(mx, 1));
    mx = fmaxf(mx, __shfl_xor(mx, 2));
    mx = fmaxf(mx, __shfl_xor(mx, 4));
    float sum = 0.f;
#pragma unroll
    for (int ci = 0; ci < 5; ++ci) { sc[ci] = __expf(sc[ci] - mx); sum += sc[ci]; }
    sum += __shfl_xor(sum, 1);
    sum += __shfl_xor(sum, 2);
    sum += __shfl_xor(sum, 4);
    const float inv = 1.0f / sum;

    const size_t twbase = ((((size_t)b * H_ + h) * T_ + t) * M_ + m) * NKT;
#pragma unroll
    for (int ci = 0; ci < 5; ++ci) {
        const int c = j + 8 * ci;
        const float w = sc[ci] * inv;
        sS[row][c] = w;
        tw[twbase + c] = w;            // f32 output
    }
    __syncthreads();

    // PV: this thread owns dims d = j*8 .. j*8+7 of row (h,m)
    float acc[8] = {0,0,0,0,0,0,0,0};
    for (int c = 0; c < NKT; ++c) {
        const float w = sS[row][c];
        const uint4* vp = (c < 8) ? (const uint4*)(sV  +  c      * STP + h * HD_)
                                  : (const uint4*)(sVs + (c - 8) * STP + h * HD_);
        const uint4 v4 = vp[j];
        acc[0] += w * blo(v4.x); acc[1] += w * bhi(v4.x);
        acc[2] += w * blo(v4.y); acc[3] += w * bhi(v4.y);
        acc[4] += w * blo(v4.z); acc[5] += w * bhi(v4.z);
        acc[6] += w * blo(v4.w); acc[7] += w * bhi(v4.w);
    }
    uint4 o;
    o.x = pack2(acc[0], acc[1]); o.y = pack2(acc[2], acc[3]);
    o.z = pack2(acc[4], acc[5]); o.w = pack2(acc[6], acc[7]);
    *(uint4*)(qkvt + baseT + m * D_ + h * HD_ + j * 8) = o;
}

// ---------------- static branch: raw masked scores ----------------
// grid = (33, H, B); chunks 0..31 = 128 temporal keys, chunk 32 = 32 static keys.
#define SKP 72
__global__ __launch_bounds__(256) void k_attn_s_scores(
    const u16* __restrict__ Qs, const u16* __restrict__ Kt, const u16* __restrict__ Ks,
    const int* __restrict__ maskT, const int* __restrict__ maskS,
    float* __restrict__ raw)
{
    const int ch = blockIdx.x;
    const int h = blockIdx.y, b = blockIdx.z;
    const int nk = (ch < 32) ? 128 : 32;
    const int k0 = ch * 128;
    __shared__ __align__(16) u16 sK[128 * SKP];
    __shared__ __align__(16) u16 sQ[32 * SKP];
    __shared__ int sM[128];
    const int tid = threadIdx.x;

    {   const int q = tid >> 3, part = tid & 7;
        ((uint4*)sQ)[q * 9 + part] =
            *(const uint4*)(Qs + ((size_t)b * S_ + q) * D_ + h * HD_ + part * 8);
    }
#pragma unroll
    for (int i = 0; i < 4; ++i) {
        const int fl = tid + i * 256;
        const int key = fl >> 3, part = fl & 7;
        if (key < nk) {
            const u16* src = (ch < 32)
                ? (Kt + ((size_t)b * TM_ + k0 + key) * D_ + h * HD_ + part * 8)
                : (Ks + ((size_t)b * S_  +      key) * D_ + h * HD_ + part * 8);
            ((uint4*)sK)[key * 9 + part] = *(const uint4*)src;
        }
    }
    if (tid < nk) sM[tid] = (ch < 32) ? maskT[(size_t)b * TM_ + k0 + tid]
                                      : maskS[b * S_ + tid];
    __syncthreads();

    const int q = tid >> 3, j = tid & 7;
    const uint4* qp = (const uint4*)(sQ + q * SKP);
    uint4 qr[8];
#pragma unroll
    for (int i8 = 0; i8 < 8; ++i8) qr[i8] = qp[i8];

    float* rowp = raw + (((size_t)b * H_ + h) * S_ + q) * NKS + k0;
    for (int ii = 0; ii < 16; ++ii) {
        const int kk = j + 8 * ii;
        if (kk >= nk) break;
        const uint4* kp = (const uint4*)(sK + kk * SKP);
        float acc = 0.f;
#pragma unroll
        for (int i8 = 0; i8 < 8; ++i8) acc += dot8(qr[i8], kp[i8]);
        rowp[kk] = acc * 0.125f + (sM[kk] ? 0.f : -1e30f);
    }
}

// ---------------- static branch: row softmax (in-place f32 + f32 sw out) --------
// grid = (S, H, B), one block per row of 4128.
__global__ __launch_bounds__(256) void k_attn_s_softmax(
    float* __restrict__ raw, float* __restrict__ sw)
{
    const int q = blockIdx.x, h = blockIdx.y, b = blockIdx.z;
    __shared__ float sRow[NKS];
    __shared__ float red[8];
    const int tid = threadIdx.x;
    const size_t base = (((size_t)b * H_ + h) * S_ + q) * NKS;

    float mx = -1e30f;
    for (int i = tid; i < NKS; i += 256) {
        const float v = raw[base + i];
        sRow[i] = v;
        mx = fmaxf(mx, v);
    }
    for (int o = 32; o; o >>= 1) mx = fmaxf(mx, __shfl_xor(mx, o));
    if ((tid & 63) == 0) red[tid >> 6] = mx;
    __syncthreads();
    mx = fmaxf(fmaxf(red[0], red[1]), fmaxf(red[2], red[3]));

    float sum = 0.f;
    for (int i = tid; i < NKS; i += 256) {
        const float e = __expf(sRow[i] - mx);
        sRow[i] = e;
        sum += e;
    }
    for (int o = 32; o; o >>= 1) sum += __shfl_xor(sum, o);
    if ((tid & 63) == 0) red[4 + (tid >> 6)] = sum;
    __syncthreads();
    sum = (red[4] + red[5]) + (red[6] + red[7]);
    const float inv = 1.0f / sum;

    for (int i = tid; i < NKS; i += 256) {
        const float w = sRow[i] * inv;
        raw[base + i] = w;          // normalized weights for PV kernel
        sw[base + i]  = w;          // f32 harness output
    }
}

// ---------------- static branch: PV ----------------
// grid = (2, H, B): 16 q-rows per block; thread = (d = tid&63, qg = tid>>6), 4 q each.
__global__ __launch_bounds__(256) void k_attn_s_pv(
    const float* __restrict__ w, const u16* __restrict__ Vt, const u16* __restrict__ Vs,
    u16* __restrict__ qkvs)
{
    const int qh = blockIdx.x, h = blockIdx.y, b = blockIdx.z;
    __shared__ float sWT[128][20];                 // [kk][q], padded
    __shared__ __align__(16) u16 sV[128 * 64];
    const int tid = threadIdx.x;
    const int d = tid & 63, qg = tid >> 6;
    float a0 = 0.f, a1 = 0.f, a2 = 0.f, a3 = 0.f;

    for (int ch = 0; ch < 33; ++ch) {
        const int nk = (ch < 32) ? 128 : 32;
        const int k0 = ch * 128;
        __syncthreads();
#pragma unroll
        for (int i = 0; i < 8; ++i) {
            const int fl = tid + i * 256;
            const int qq = fl >> 7, kk = fl & 127;
            sWT[kk][qq] = (kk < nk)
                ? w[(((size_t)b * H_ + h) * S_ + qh * 16 + qq) * NKS + k0 + kk] : 0.f;
        }
#pragma unroll
        for (int i = 0; i < 4; ++i) {
            const int fl = tid + i * 256;
            const int key = fl >> 3, part = fl & 7;
            if (key < nk) {
                const u16* src = (ch < 32)
                    ? (Vt + ((size_t)b * TM_ + k0 + key) * D_ + h * HD_ + part * 8)
                    : (Vs + ((size_t)b * S_  +      key) * D_ + h * HD_ + part * 8);
                ((uint4*)sV)[fl] = *(const uint4*)src;
            }
        }
        __syncthreads();
        for (int kk = 0; kk < nk; ++kk) {
            const float v = b2f(sV[kk * 64 + d]);
            const float4 w4 = *(const float4*)&sWT[kk][qg * 4];
            a0 += w4.x * v; a1 += w4.y * v; a2 += w4.z * v; a3 += w4.w * v;
        }
    }
    const size_t ob = ((size_t)b * S_ + qh * 16 + qg * 4) * D_ + h * HD_ + d;
    qkvs[ob         ] = f2b(a0);
    qkvs[ob +     D_] = f2b(a1);
    qkvs[ob + 2 * D_] = f2b(a2);
    qkvs[ob + 3 * D_] = f2b(a3);
}

// ---------------- launch ----------------
extern "C" void kernel_launch(void* const* d_in, const int* in_sizes, int n_in,
                              void* d_out, int out_size, void* d_ws, size_t ws_size,
                              hipStream_t stream)
{
    const float* q_t = (const float*)d_in[0];
    const float* q_s = (const float*)d_in[1];
    const float* k_t = (const float*)d_in[2];
    const float* v_t = (const float*)d_in[3];
    const float* k_s = (const float*)d_in[4];
    const float* v_s = (const float*)d_in[5];
    const float* q_w = (const float*)d_in[6];
    const float* q_b = (const float*)d_in[7];
    const float* k_w = (const float*)d_in[8];
    const float* k_b = (const float*)d_in[9];
    const float* v_w = (const float*)d_in[10];
    const float* v_b = (const float*)d_in[11];
    const float* o_w = (const float*)d_in[12];
    const float* o_b = (const float*)d_in[13];
    const int* maskT = (const int*)d_in[14];
    // d_in[15] = mask_fcst: unused by the reference
    const int* maskS = (const int*)d_in[16];
    float* out = (float*)d_out;       // FLOAT32 outputs (reference output dtype)

    char* ws = (char*)d_ws;
    u16*   Kt   = (u16*)(ws + 0);
    u16*   Vt   = (u16*)(ws + 33554432);
    u16*   QKVt = (u16*)(ws + 67108864);
    u16*   Qs   = (u16*)(ws + 100663296);
    u16*   Ks   = (u16*)(ws + 100925440);
    u16*   Vs   = (u16*)(ws + 101187584);
    u16*   QKVs = (u16*)(ws + 101449728);
    u16*   Qt   = (u16*)(ws + 101711872);
    float* raw  = (float*)(ws + 101711872);  // aliases Qt (dead before scores run)
    if (ws_size < 135528448) return;         // required workspace

    float* out_t = out;                 // [B,T,M,D]
    float* out_s = out + 16777216;      // [B,S,D]
    float* tw    = out + 16908288;      // [B,H,T,M,40]
    float* sw    = out + 27394048;      // [B,H,S,4128]

    const dim3 blk(256);
    k_gemm_m<0,0><<<dim3(1024), blk, 0, stream>>>(q_t, q_w, q_b, Qt);
    k_gemm_m<0,0><<<dim3(1024), blk, 0, stream>>>(k_t, k_w, k_b, Kt);
    k_gemm_m<0,0><<<dim3(1024), blk, 0, stream>>>(v_t, v_w, v_b, Vt);
    k_gemm_m<0,0><<<dim3(8),    blk, 0, stream>>>(q_s, q_w, q_b, Qs);
    k_gemm_m<0,0><<<dim3(8),    blk, 0, stream>>>(k_s, k_w, k_b, Ks);
    k_gemm_m<0,0><<<dim3(8),    blk, 0, stream>>>(v_s, v_w, v_b, Vs);

    k_attn_t<<<dim3(512, 16), blk, 0, stream>>>(Qt, Kt, Vt, Ks, Vs, maskT, maskS, tw, QKVt);

    k_attn_s_scores<<<dim3(33, 4, 16), blk, 0, stream>>>(Qs, Kt, Ks, maskT, maskS, raw);
    k_attn_s_softmax<<<dim3(32, 4, 16), blk, 0, stream>>>(raw, sw);
    k_attn_s_pv<<<dim3(2, 4, 16), blk, 0, stream>>>(raw, Vt, Vs, QKVs);

    k_gemm_m<1,1><<<dim3(1024), blk, 0, stream>>>(QKVt, o_w, o_b, out_t);
    k_gemm_m<1,1><<<dim3(8),    blk, 0, stream>>>(QKVs, o_w, o_b, out_s);
}

// Round 6
// 382.076 us; speedup vs baseline: 2.6532x; 1.3439x over previous
//
#include <hip/hip_runtime.h>

// ---------------- constants ----------------
#define B_   16
#define T_   512
#define M_   8
#define S_   32
#define D_   256
#define H_   4
#define HD_  64
#define TM_  4096      // T*M
#define NKT  40        // M+S
#define NKS  4128      // T*M+S

typedef unsigned short u16;
typedef __attribute__((ext_vector_type(8))) short bf16x8;
typedef __attribute__((ext_vector_type(4))) float f32x4;

// ---------------- bf16 helpers ----------------
__device__ __forceinline__ u16 f2b(float f) {
    union { float f; unsigned u; } v; v.f = f;
    unsigned r = v.u + 0x7FFF + ((v.u >> 16) & 1);   // RNE
    return (u16)(r >> 16);
}
__device__ __forceinline__ float blo(unsigned u) {
    union { unsigned i; float f; } v; v.i = u << 16; return v.f;
}
__device__ __forceinline__ float bhi(unsigned u) {
    union { unsigned i; float f; } v; v.i = u & 0xFFFF0000u; return v.f;
}
__device__ __forceinline__ float b2f(u16 u) {
    union { unsigned i; float f; } v; v.i = ((unsigned)u) << 16; return v.f;
}
__device__ __forceinline__ float dot8(uint4 a, uint4 b) {
    return blo(a.x)*blo(b.x) + bhi(a.x)*bhi(b.x)
         + blo(a.y)*blo(b.y) + bhi(a.y)*bhi(b.y)
         + blo(a.z)*blo(b.z) + bhi(a.z)*bhi(b.z)
         + blo(a.w)*blo(b.w) + bhi(a.w)*bhi(b.w);
}
__device__ __forceinline__ unsigned pack2(float lo, float hi) {
    return (unsigned)f2b(lo) | ((unsigned)f2b(hi) << 16);
}
__device__ __forceinline__ uint4 cvt8(float4 a, float4 b) {
    uint4 r;
    r.x = pack2(a.x, a.y); r.y = pack2(a.z, a.w);
    r.z = pack2(b.x, b.y); r.w = pack2(b.z, b.w);
    return r;
}

// ---------------- MFMA GEMM: Y[r][c] = X[r]·W[c] + bias[c] ----------------
// Tile: 64 rows x 256 cols (whole N) per block, BK=32, 4 waves.
template<int XBF, int OUTF32>
__global__ __launch_bounds__(256) void k_gemm_m(const void* __restrict__ Xv,
                                                const float* __restrict__ W,
                                                const float* __restrict__ bias,
                                                void* __restrict__ Yv)
{
    __shared__ __align__(16) u16 sA[64 * 32];
    __shared__ __align__(16) u16 sB[256 * 32];
    const int tid = threadIdx.x;
    const size_t r0 = (size_t)blockIdx.x * 64;
    const int wave = tid >> 6, lane = tid & 63;
    const int rbase = lane & 15, kseg = (lane >> 4) * 8;

    f32x4 acc[4][4];
#pragma unroll
    for (int i = 0; i < 4; ++i)
#pragma unroll
        for (int j = 0; j < 4; ++j) acc[i][j] = (f32x4){0, 0, 0, 0};

    const int arow = tid >> 2, aseg = tid & 3;

    for (int k0 = 0; k0 < 256; k0 += 32) {
        uint4 aW;
        if (XBF) {
            aW = *(const uint4*)((const u16*)Xv + (r0 + arow) * 256 + k0 + aseg * 8);
        } else {
            const float* gA = (const float*)Xv + (r0 + arow) * 256 + k0 + aseg * 8;
            aW = cvt8(*(const float4*)gA, *(const float4*)(gA + 4));
        }
        uint4 bW[4];
#pragma unroll
        for (int i = 0; i < 4; ++i) {
            const int s = i * 256 + tid;
            const float* gB = W + (size_t)(s >> 2) * 256 + k0 + (s & 3) * 8;
            bW[i] = cvt8(*(const float4*)gB, *(const float4*)(gB + 4));
        }
        if (k0) __syncthreads();
        *(uint4*)(sA + tid * 8) = aW;
#pragma unroll
        for (int i = 0; i < 4; ++i)
            *(uint4*)(sB + (i * 256 + tid) * 8) = bW[i];
        __syncthreads();

        bf16x8 a[4], b[4];
#pragma unroll
        for (int f = 0; f < 4; ++f)
            a[f] = *(const bf16x8*)(sA + (f * 16 + rbase) * 32 + kseg);
#pragma unroll
        for (int f = 0; f < 4; ++f)
            b[f] = *(const bf16x8*)(sB + (wave * 64 + f * 16 + rbase) * 32 + kseg);
#pragma unroll
        for (int rf = 0; rf < 4; ++rf)
#pragma unroll
            for (int cf = 0; cf < 4; ++cf)
                acc[rf][cf] = __builtin_amdgcn_mfma_f32_16x16x32_bf16(
                    a[rf], b[cf], acc[rf][cf], 0, 0, 0);
    }

    const int orow = (lane >> 4) * 4, ocol = lane & 15;
#pragma unroll
    for (int cf = 0; cf < 4; ++cf) {
        const int col = wave * 64 + cf * 16 + ocol;
        const float bv = bias[col];
#pragma unroll
        for (int rf = 0; rf < 4; ++rf)
#pragma unroll
            for (int r = 0; r < 4; ++r) {
                const size_t row = r0 + rf * 16 + orow + r;
                const float y = acc[rf][cf][r] + bv;
                if (OUTF32) ((float*)Yv)[row * 256 + col] = y;
                else        ((u16*) Yv)[row * 256 + col] = f2b(y);
            }
    }
}

// ---------------- temporal attention: one block per (t,b) ----------------
#define STP 264   // padded LDS row stride (u16)
__global__ __launch_bounds__(256) void k_attn_t(
    const u16* __restrict__ Qt, const u16* __restrict__ Kt, const u16* __restrict__ Vt,
    const u16* __restrict__ Ks, const u16* __restrict__ Vs,
    const int* __restrict__ maskT, const int* __restrict__ maskS,
    float* __restrict__ tw, u16* __restrict__ qkvt)
{
    const int t = blockIdx.x, b = blockIdx.y;
    __shared__ __align__(16) u16 sQ[8 * STP], sK[8 * STP], sV[8 * STP];
    __shared__ __align__(16) u16 sKs[32 * STP], sVs[32 * STP];
    __shared__ float sS[32][NKT];
    __shared__ int smT[8], smS[32];
    const int tid = threadIdx.x;
    const size_t baseT = ((size_t)b * T_ + t) * (M_ * D_);

    {   const uint4* gq = (const uint4*)(Qt + baseT);
        const uint4* gk = (const uint4*)(Kt + baseT);
        const uint4* gv = (const uint4*)(Vt + baseT);
        const int r1 = tid >> 5, s1 = tid & 31, d1 = r1 * 33 + s1;
        ((uint4*)sQ)[d1] = gq[tid];
        ((uint4*)sK)[d1] = gk[tid];
        ((uint4*)sV)[d1] = gv[tid];
        const uint4* gks = (const uint4*)(Ks + (size_t)b * (S_ * D_));
        const uint4* gvs = (const uint4*)(Vs + (size_t)b * (S_ * D_));
#pragma unroll
        for (int i = 0; i < 4; ++i) {
            const int fl = tid + i * 256;
            const int r2 = fl >> 5, s2 = fl & 31, d2 = r2 * 33 + s2;
            ((uint4*)sKs)[d2] = gks[fl];
            ((uint4*)sVs)[d2] = gvs[fl];
        }
        if (tid < 8)  smT[tid] = maskT[((size_t)b * T_ + t) * M_ + tid];
        if (tid < 32) smS[tid] = maskS[b * S_ + tid];
    }
    __syncthreads();

    const int row = tid >> 3;
    const int h = row >> 3, m = row & 7;
    const int j = tid & 7;

    const uint4* qp = (const uint4*)(sQ + m * STP + h * HD_);
    uint4 qr[8];
#pragma unroll
    for (int i8 = 0; i8 < 8; ++i8) qr[i8] = qp[i8];

    float sc[5];
#pragma unroll
    for (int ci = 0; ci < 5; ++ci) {
        const int c = j + 8 * ci;
        const uint4* kp = (c < 8) ? (const uint4*)(sK  +  c      * STP + h * HD_)
                                  : (const uint4*)(sKs + (c - 8) * STP + h * HD_);
        float acc = 0.f;
#pragma unroll
        for (int i8 = 0; i8 < 8; ++i8) acc += dot8(qr[i8], kp[i8]);
        const int valid = (c < 8) ? smT[c] : smS[c - 8];
        sc[ci] = valid ? acc * 0.125f : -1e30f;
    }

    float mx = fmaxf(fmaxf(fmaxf(sc[0], sc[1]), fmaxf(sc[2], sc[3])), sc[4]);
    mx = fmaxf(mx, __shfl_xor(mx, 1));
    mx = fmaxf(mx, __shfl_xor(mx, 2));
    mx = fmaxf(mx, __shfl_xor(mx, 4));
    float sum = 0.f;
#pragma unroll
    for (int ci = 0; ci < 5; ++ci) { sc[ci] = __expf(sc[ci] - mx); sum += sc[ci]; }
    sum += __shfl_xor(sum, 1);
    sum += __shfl_xor(sum, 2);
    sum += __shfl_xor(sum, 4);
    const float inv = 1.0f / sum;

    const size_t twbase = ((((size_t)b * H_ + h) * T_ + t) * M_ + m) * NKT;
#pragma unroll
    for (int ci = 0; ci < 5; ++ci) {
        const int c = j + 8 * ci;
        const float w = sc[ci] * inv;
        sS[row][c] = w;
        tw[twbase + c] = w;
    }
    __syncthreads();

    float acc[8] = {0,0,0,0,0,0,0,0};
    for (int c = 0; c < NKT; ++c) {
        const float w = sS[row][c];
        const uint4* vp = (c < 8) ? (const uint4*)(sV  +  c      * STP + h * HD_)
                                  : (const uint4*)(sVs + (c - 8) * STP + h * HD_);
        const uint4 v4 = vp[j];
        acc[0] += w * blo(v4.x); acc[1] += w * bhi(v4.x);
        acc[2] += w * blo(v4.y); acc[3] += w * bhi(v4.y);
        acc[4] += w * blo(v4.z); acc[5] += w * bhi(v4.z);
        acc[6] += w * blo(v4.w); acc[7] += w * bhi(v4.w);
    }
    uint4 o;
    o.x = pack2(acc[0], acc[1]); o.y = pack2(acc[2], acc[3]);
    o.z = pack2(acc[4], acc[5]); o.w = pack2(acc[6], acc[7]);
    *(uint4*)(qkvt + baseT + m * D_ + h * HD_ + j * 8) = o;
}

// ---------------- static branch: raw masked scores ----------------
#define SKP 72
__global__ __launch_bounds__(256) void k_attn_s_scores(
    const u16* __restrict__ Qs, const u16* __restrict__ Kt, const u16* __restrict__ Ks,
    const int* __restrict__ maskT, const int* __restrict__ maskS,
    float* __restrict__ raw)
{
    const int ch = blockIdx.x;
    const int h = blockIdx.y, b = blockIdx.z;
    const int nk = (ch < 32) ? 128 : 32;
    const int k0 = ch * 128;
    __shared__ __align__(16) u16 sK[128 * SKP];
    __shared__ __align__(16) u16 sQ[32 * SKP];
    __shared__ int sM[128];
    const int tid = threadIdx.x;

    {   const int q = tid >> 3, part = tid & 7;
        ((uint4*)sQ)[q * 9 + part] =
            *(const uint4*)(Qs + ((size_t)b * S_ + q) * D_ + h * HD_ + part * 8);
    }
#pragma unroll
    for (int i = 0; i < 4; ++i) {
        const int fl = tid + i * 256;
        const int key = fl >> 3, part = fl & 7;
        if (key < nk) {
            const u16* src = (ch < 32)
                ? (Kt + ((size_t)b * TM_ + k0 + key) * D_ + h * HD_ + part * 8)
                : (Ks + ((size_t)b * S_  +      key) * D_ + h * HD_ + part * 8);
            ((uint4*)sK)[key * 9 + part] = *(const uint4*)src;
        }
    }
    if (tid < nk) sM[tid] = (ch < 32) ? maskT[(size_t)b * TM_ + k0 + tid]
                                      : maskS[b * S_ + tid];
    __syncthreads();

    const int q = tid >> 3, j = tid & 7;
    const uint4* qp = (const uint4*)(sQ + q * SKP);
    uint4 qr[8];
#pragma unroll
    for (int i8 = 0; i8 < 8; ++i8) qr[i8] = qp[i8];

    float* rowp = raw + (((size_t)b * H_ + h) * S_ + q) * NKS + k0;
    for (int ii = 0; ii < 16; ++ii) {
        const int kk = j + 8 * ii;
        if (kk >= nk) break;
        const uint4* kp = (const uint4*)(sK + kk * SKP);
        float acc = 0.f;
#pragma unroll
        for (int i8 = 0; i8 < 8; ++i8) acc += dot8(qr[i8], kp[i8]);
        rowp[kk] = acc * 0.125f + (sM[kk] ? 0.f : -1e30f);
    }
}

// ---------------- static branch: row softmax ----------------
__global__ __launch_bounds__(256) void k_attn_s_softmax(
    float* __restrict__ raw, float* __restrict__ sw)
{
    const int q = blockIdx.x, h = blockIdx.y, b = blockIdx.z;
    __shared__ float sRow[NKS];
    __shared__ float red[8];
    const int tid = threadIdx.x;
    const size_t base = (((size_t)b * H_ + h) * S_ + q) * NKS;

    float mx = -1e30f;
    for (int i = tid; i < NKS; i += 256) {
        const float v = raw[base + i];
        sRow[i] = v;
        mx = fmaxf(mx, v);
    }
    for (int o = 32; o; o >>= 1) mx = fmaxf(mx, __shfl_xor(mx, o));
    if ((tid & 63) == 0) red[tid >> 6] = mx;
    __syncthreads();
    mx = fmaxf(fmaxf(red[0], red[1]), fmaxf(red[2], red[3]));

    float sum = 0.f;
    for (int i = tid; i < NKS; i += 256) {
        const float e = __expf(sRow[i] - mx);
        sRow[i] = e;
        sum += e;
    }
    for (int o = 32; o; o >>= 1) sum += __shfl_xor(sum, o);
    if ((tid & 63) == 0) red[4 + (tid >> 6)] = sum;
    __syncthreads();
    sum = (red[4] + red[5]) + (red[6] + red[7]);
    const float inv = 1.0f / sum;

    for (int i = tid; i < NKS; i += 256) {
        const float w = sRow[i] * inv;
        raw[base + i] = w;
        sw[base + i]  = w;
    }
}

// ---------------- static branch: split-K PV partials ----------------
// grid = (33, H, B): chunk ch<32 = temporal keys ch*128..+127, ch==32 = 32 static.
// Block: stage w (f32, [q][kk] padded 132) + V (bf16 linear) in LDS; thread
// (d = tid&63, qg = tid>>6) accumulates 8 q-outputs over the chunk's keys.
__global__ __launch_bounds__(256) void k_attn_s_pv_part(
    const float* __restrict__ w, const u16* __restrict__ Vt, const u16* __restrict__ Vs,
    float* __restrict__ part)
{
    const int ch = blockIdx.x, h = blockIdx.y, b = blockIdx.z;
    const int nk = (ch < 32) ? 128 : 32;
    const int k0 = ch * 128;
    __shared__ float sW[32][132];                  // [q][kk], stride 132: f4-aligned, cf-free
    __shared__ __align__(16) u16 sV[128 * 64];
    const int tid = threadIdx.x;

#pragma unroll
    for (int i = 0; i < 4; ++i) {                  // w: 32 q x nk f32, float4 loads
        const int fl = tid + i * 256;              // 0..1023
        const int q = fl >> 5, k4 = fl & 31;
        if (k4 * 4 < nk)
            *(float4*)&sW[q][k4 * 4] =
                *(const float4*)(w + (((size_t)b * H_ + h) * S_ + q) * NKS + k0 + k4 * 4);
    }
#pragma unroll
    for (int i = 0; i < 4; ++i) {                  // V: nk x 64 bf16, uint4 loads
        const int fl = tid + i * 256;
        const int key = fl >> 3, pp = fl & 7;
        if (key < nk) {
            const u16* src = (ch < 32)
                ? (Vt + ((size_t)b * TM_ + k0 + key) * D_ + h * HD_ + pp * 8)
                : (Vs + ((size_t)b * S_  +      key) * D_ + h * HD_ + pp * 8);
            ((uint4*)sV)[fl] = *(const uint4*)src;
        }
    }
    __syncthreads();

    const int d = tid & 63, qg = tid >> 6;         // 8 q's per thread
    float acc[8] = {0,0,0,0,0,0,0,0};
    for (int kk = 0; kk < nk; kk += 4) {
        const float v0 = b2f(sV[(kk + 0) * 64 + d]);
        const float v1 = b2f(sV[(kk + 1) * 64 + d]);
        const float v2 = b2f(sV[(kk + 2) * 64 + d]);
        const float v3 = b2f(sV[(kk + 3) * 64 + d]);
#pragma unroll
        for (int j = 0; j < 8; ++j) {              // broadcast reads (wave-uniform addr)
            const float4 wv = *(const float4*)&sW[qg * 8 + j][kk];
            acc[j] += wv.x * v0 + wv.y * v1 + wv.z * v2 + wv.w * v3;
        }
    }

    float* pb = part + (((size_t)ch * B_ + b) * H_ + h) * 2048;
#pragma unroll
    for (int j = 0; j < 8; ++j)
        pb[(qg * 8 + j) * 64 + d] = acc[j];
}

// ---------------- static branch: PV reduce (33 partials -> QKVs bf16) ----------
__global__ __launch_bounds__(256) void k_attn_s_pv_red(
    const float* __restrict__ part, u16* __restrict__ qkvs)
{
    const int h = blockIdx.x, b = blockIdx.y;
    const int tid = threadIdx.x;
    for (int i = tid; i < 2048; i += 256) {
        float s = 0.f;
#pragma unroll
        for (int c = 0; c < 33; ++c)
            s += part[(((size_t)c * B_ + b) * H_ + h) * 2048 + i];
        const int q = i >> 6, d = i & 63;
        qkvs[((size_t)b * S_ + q) * D_ + h * HD_ + d] = f2b(s);
    }
}

// ---------------- launch ----------------
extern "C" void kernel_launch(void* const* d_in, const int* in_sizes, int n_in,
                              void* d_out, int out_size, void* d_ws, size_t ws_size,
                              hipStream_t stream)
{
    const float* q_t = (const float*)d_in[0];
    const float* q_s = (const float*)d_in[1];
    const float* k_t = (const float*)d_in[2];
    const float* v_t = (const float*)d_in[3];
    const float* k_s = (const float*)d_in[4];
    const float* v_s = (const float*)d_in[5];
    const float* q_w = (const float*)d_in[6];
    const float* q_b = (const float*)d_in[7];
    const float* k_w = (const float*)d_in[8];
    const float* k_b = (const float*)d_in[9];
    const float* v_w = (const float*)d_in[10];
    const float* v_b = (const float*)d_in[11];
    const float* o_w = (const float*)d_in[12];
    const float* o_b = (const float*)d_in[13];
    const int* maskT = (const int*)d_in[14];
    // d_in[15] = mask_fcst: unused by the reference
    const int* maskS = (const int*)d_in[16];
    float* out = (float*)d_out;

    char* ws = (char*)d_ws;
    u16*   Kt   = (u16*)(ws + 0);
    u16*   Vt   = (u16*)(ws + 33554432);
    u16*   QKVt = (u16*)(ws + 67108864);
    float* part = (float*)(ws + 67108864);   // aliases QKVt (dead after out_t GEMM)
    u16*   Qs   = (u16*)(ws + 100663296);
    u16*   Ks   = (u16*)(ws + 100925440);
    u16*   Vs   = (u16*)(ws + 101187584);
    u16*   QKVs = (u16*)(ws + 101449728);
    u16*   Qt   = (u16*)(ws + 101711872);
    float* raw  = (float*)(ws + 101711872);  // aliases Qt (dead before scores run)
    if (ws_size < 135528448) return;         // required workspace

    float* out_t = out;                 // [B,T,M,D]
    float* out_s = out + 16777216;      // [B,S,D]
    float* tw    = out + 16908288;      // [B,H,T,M,40]
    float* sw    = out + 27394048;      // [B,H,S,4128]

    const dim3 blk(256);
    k_gemm_m<0,0><<<dim3(1024), blk, 0, stream>>>(q_t, q_w, q_b, Qt);
    k_gemm_m<0,0><<<dim3(1024), blk, 0, stream>>>(k_t, k_w, k_b, Kt);
    k_gemm_m<0,0><<<dim3(1024), blk, 0, stream>>>(v_t, v_w, v_b, Vt);
    k_gemm_m<0,0><<<dim3(8),    blk, 0, stream>>>(q_s, q_w, q_b, Qs);
    k_gemm_m<0,0><<<dim3(8),    blk, 0, stream>>>(k_s, k_w, k_b, Ks);
    k_gemm_m<0,0><<<dim3(8),    blk, 0, stream>>>(v_s, v_w, v_b, Vs);

    k_attn_t<<<dim3(512, 16), blk, 0, stream>>>(Qt, Kt, Vt, Ks, Vs, maskT, maskS, tw, QKVt);

    // out_t projection FIRST: frees QKVt so PV partials can alias it.
    k_gemm_m<1,1><<<dim3(1024), blk, 0, stream>>>(QKVt, o_w, o_b, out_t);

    k_attn_s_scores<<<dim3(33, 4, 16), blk, 0, stream>>>(Qs, Kt, Ks, maskT, maskS, raw);
    k_attn_s_softmax<<<dim3(32, 4, 16), blk, 0, stream>>>(raw, sw);
    k_attn_s_pv_part<<<dim3(33, 4, 16), blk, 0, stream>>>(raw, Vt, Vs, part);
    k_attn_s_pv_red<<<dim3(4, 16), blk, 0, stream>>>(part, QKVs);

    k_gemm_m<1,1><<<dim3(8),    blk, 0, stream>>>(QKVs, o_w, o_b, out_s);
}

// Round 7
// 330.053 us; speedup vs baseline: 3.0714x; 1.1576x over previous
//
#include <hip/hip_runtime.h>

// ---------------- constants ----------------
#define B_   16
#define T_   512
#define M_   8
#define S_   32
#define D_   256
#define H_   4
#define HD_  64
#define TM_  4096      // T*M
#define NKT  40        // M+S
#define NKS  4128      // T*M+S

typedef unsigned short u16;
typedef __attribute__((ext_vector_type(8))) short bf16x8;
typedef __attribute__((ext_vector_type(4))) float f32x4;

// ---------------- bf16 helpers ----------------
__device__ __forceinline__ u16 f2b(float f) {
    union { float f; unsigned u; } v; v.f = f;
    unsigned r = v.u + 0x7FFF + ((v.u >> 16) & 1);   // RNE
    return (u16)(r >> 16);
}
__device__ __forceinline__ float blo(unsigned u) {
    union { unsigned i; float f; } v; v.i = u << 16; return v.f;
}
__device__ __forceinline__ float bhi(unsigned u) {
    union { unsigned i; float f; } v; v.i = u & 0xFFFF0000u; return v.f;
}
__device__ __forceinline__ float b2f(u16 u) {
    union { unsigned i; float f; } v; v.i = ((unsigned)u) << 16; return v.f;
}
__device__ __forceinline__ unsigned pack2(float lo, float hi) {
    return (unsigned)f2b(lo) | ((unsigned)f2b(hi) << 16);
}
__device__ __forceinline__ uint4 cvt8(float4 a, float4 b) {
    uint4 r;
    r.x = pack2(a.x, a.y); r.y = pack2(a.z, a.w);
    r.z = pack2(b.x, b.y); r.w = pack2(b.z, b.w);
    return r;
}

// ---------------- MFMA GEMM: Y[r][c] = X[r]·W[c] + bias[c] ----------------
// Tile: 64 rows x 256 cols (whole N) per block, BK=32, 4 waves.
template<int XBF, int OUTF32>
__global__ __launch_bounds__(256) void k_gemm_m(const void* __restrict__ Xv,
                                                const float* __restrict__ W,
                                                const float* __restrict__ bias,
                                                void* __restrict__ Yv)
{
    __shared__ __align__(16) u16 sA[64 * 32];
    __shared__ __align__(16) u16 sB[256 * 32];
    const int tid = threadIdx.x;
    const size_t r0 = (size_t)blockIdx.x * 64;
    const int wave = tid >> 6, lane = tid & 63;
    const int rbase = lane & 15, kseg = (lane >> 4) * 8;

    f32x4 acc[4][4];
#pragma unroll
    for (int i = 0; i < 4; ++i)
#pragma unroll
        for (int j = 0; j < 4; ++j) acc[i][j] = (f32x4){0, 0, 0, 0};

    const int arow = tid >> 2, aseg = tid & 3;

    for (int k0 = 0; k0 < 256; k0 += 32) {
        uint4 aW;
        if (XBF) {
            aW = *(const uint4*)((const u16*)Xv + (r0 + arow) * 256 + k0 + aseg * 8);
        } else {
            const float* gA = (const float*)Xv + (r0 + arow) * 256 + k0 + aseg * 8;
            aW = cvt8(*(const float4*)gA, *(const float4*)(gA + 4));
        }
        uint4 bW[4];
#pragma unroll
        for (int i = 0; i < 4; ++i) {
            const int s = i * 256 + tid;
            const float* gB = W + (size_t)(s >> 2) * 256 + k0 + (s & 3) * 8;
            bW[i] = cvt8(*(const float4*)gB, *(const float4*)(gB + 4));
        }
        if (k0) __syncthreads();
        *(uint4*)(sA + tid * 8) = aW;
#pragma unroll
        for (int i = 0; i < 4; ++i)
            *(uint4*)(sB + (i * 256 + tid) * 8) = bW[i];
        __syncthreads();

        bf16x8 a[4], b[4];
#pragma unroll
        for (int f = 0; f < 4; ++f)
            a[f] = *(const bf16x8*)(sA + (f * 16 + rbase) * 32 + kseg);
#pragma unroll
        for (int f = 0; f < 4; ++f)
            b[f] = *(const bf16x8*)(sB + (wave * 64 + f * 16 + rbase) * 32 + kseg);
#pragma unroll
        for (int rf = 0; rf < 4; ++rf)
#pragma unroll
            for (int cf = 0; cf < 4; ++cf)
                acc[rf][cf] = __builtin_amdgcn_mfma_f32_16x16x32_bf16(
                    a[rf], b[cf], acc[rf][cf], 0, 0, 0);
    }

    const int orow = (lane >> 4) * 4, ocol = lane & 15;
#pragma unroll
    for (int cf = 0; cf < 4; ++cf) {
        const int col = wave * 64 + cf * 16 + ocol;
        const float bv = bias[col];
#pragma unroll
        for (int rf = 0; rf < 4; ++rf)
#pragma unroll
            for (int r = 0; r < 4; ++r) {
                const size_t row = r0 + rf * 16 + orow + r;
                const float y = acc[rf][cf][r] + bv;
                if (OUTF32) ((float*)Yv)[row * 256 + col] = y;
                else        ((u16*) Yv)[row * 256 + col] = f2b(y);
            }
    }
}

// ---------------- temporal attention (MFMA): one block per (t-pair, b) --------
// 16 MFMA rows = (t0 m0-7, t1 m0-7); 4 waves = 4 heads. Score tiles: 1 temporal
// (16 keys: t0 k0-7, t1 k0-7; cross-t masked) + 2 static (32 keys). Softmax in
// C-frag layout; P->bf16 LDS; PV via MFMA with V^T staged per head.
__global__ __launch_bounds__(256) void k_attn_t(
    const u16* __restrict__ Qt, const u16* __restrict__ Kt, const u16* __restrict__ Vt,
    const u16* __restrict__ Ks, const u16* __restrict__ Vs,
    const int* __restrict__ maskT, const int* __restrict__ maskS,
    float* __restrict__ tw, u16* __restrict__ qkvt)
{
    const int tp = blockIdx.x, b = blockIdx.y;
    const int t0 = tp * 2;
    __shared__ __align__(16) u16 sQ [4 * 2 * 16 * 32];   // [h][ks][row16][32]
    __shared__ __align__(16) u16 sKT[4 * 2 * 16 * 32];   // temporal K rows (t,k)
    __shared__ __align__(16) u16 sKS[4 * 2 * 32 * 32];   // static K rows
    __shared__ __align__(16) u16 sVT[4 * 64 * 72];       // [h][d64][key72] V^T, keys48-63=0
    __shared__ __align__(16) u16 sP [4 * 16 * 72];       // [h][row][key72]
    __shared__ int smT[2][8];
    __shared__ int smS[32];
    const int tid = threadIdx.x;

    // ---- stage Q, Kt: 16 rows x 256 each ----
#pragma unroll
    for (int i = 0; i < 2; ++i) {
        const int fl = tid + i * 256;
        const int r = fl >> 5, c32 = fl & 31;
        const int h = c32 >> 3, ks = (c32 >> 2) & 1, seg = c32 & 3;
        const size_t src = (((size_t)b * T_ + t0 + (r >> 3)) * 8 + (r & 7)) * 256 + c32 * 8;
        const int dst = h * 1024 + ks * 512 + r * 32 + seg * 8;
        *(uint4*)(sQ  + dst) = *(const uint4*)(Qt + src);
        *(uint4*)(sKT + dst) = *(const uint4*)(Kt + src);
    }
    // ---- stage Ks: 32 x 256 ----
#pragma unroll
    for (int i = 0; i < 4; ++i) {
        const int fl = tid + i * 256;
        const int r = fl >> 5, c32 = fl & 31;
        const int h = c32 >> 3, ks = (c32 >> 2) & 1, seg = c32 & 3;
        *(uint4*)(sKS + h * 2048 + ks * 1024 + r * 32 + seg * 8) =
            *(const uint4*)(Ks + ((size_t)b * S_ + r) * 256 + c32 * 8);
    }
    // ---- stage V^T: key = tid&63 (48 data + 16 zero), 32 d-segs each ----
    {
        const int key = tid & 63, dg = tid >> 6;
        const u16* vrow = nullptr;
        if (key < 16)      vrow = Vt + (((size_t)b * T_ + t0 + (key >> 3)) * 8 + (key & 7)) * 256;
        else if (key < 48) vrow = Vs + ((size_t)b * S_ + (key - 16)) * 256;
#pragma unroll
        for (int i = 0; i < 8; ++i) {
            const int dseg = dg * 8 + i;           // 0..31
            uint4 v = {0, 0, 0, 0};
            if (vrow) v = *(const uint4*)(vrow + dseg * 8);
            const int h = dseg >> 3, dl0 = (dseg & 7) * 8;
            const u16* pv = (const u16*)&v;
#pragma unroll
            for (int j = 0; j < 8; ++j)
                sVT[h * 4608 + (dl0 + j) * 72 + key] = pv[j];
        }
    }
    if (tid < 16) smT[tid >> 3][tid & 7] =
        maskT[((size_t)b * T_ + t0 + (tid >> 3)) * 8 + (tid & 7)];
    if (tid < 32) smS[tid] = maskS[b * S_ + tid];
    __syncthreads();

    const int h = tid >> 6, lane = tid & 63;
    const int c = lane & 15, g = lane >> 4, th = g >> 1;   // th = t-half of this lane's rows

    // ---- scores: 6 MFMA ----
    f32x4 at = {0,0,0,0}, as0 = {0,0,0,0}, as1 = {0,0,0,0};
#pragma unroll
    for (int ks = 0; ks < 2; ++ks) {
        bf16x8 aq = *(const bf16x8*)(sQ  + h * 1024 + ks * 512 + c * 32 + g * 8);
        bf16x8 bt = *(const bf16x8*)(sKT + h * 1024 + ks * 512 + c * 32 + g * 8);
        bf16x8 b0 = *(const bf16x8*)(sKS + h * 2048 + ks * 1024 + c * 32 + g * 8);
        bf16x8 b1 = *(const bf16x8*)(sKS + h * 2048 + ks * 1024 + 512 + c * 32 + g * 8);
        at  = __builtin_amdgcn_mfma_f32_16x16x32_bf16(aq, bt, at, 0, 0, 0);
        as0 = __builtin_amdgcn_mfma_f32_16x16x32_bf16(aq, b0, as0, 0, 0, 0);
        as1 = __builtin_amdgcn_mfma_f32_16x16x32_bf16(aq, b1, as1, 0, 0, 0);
    }

    // ---- mask + softmax in C-frag layout (col=c, row=g*4+r) ----
    const int vt = ((c >> 3) == th) ? smT[th][c & 7] : 0;  // lane-uniform across regs
    const int v0 = smS[c], v1 = smS[16 + c];
    float st[4], s0[4], s1[4], mx[4];
#pragma unroll
    for (int r = 0; r < 4; ++r) {
        st[r] = vt ? at[r]  * 0.125f : -1e30f;
        s0[r] = v0 ? as0[r] * 0.125f : -1e30f;
        s1[r] = v1 ? as1[r] * 0.125f : -1e30f;
        mx[r] = fmaxf(fmaxf(st[r], s0[r]), s1[r]);
    }
#pragma unroll
    for (int o = 1; o < 16; o <<= 1)
#pragma unroll
        for (int r = 0; r < 4; ++r) mx[r] = fmaxf(mx[r], __shfl_xor(mx[r], o));
    float pt[4], p0[4], p1[4], sum[4];
#pragma unroll
    for (int r = 0; r < 4; ++r) {
        pt[r] = __expf(st[r] - mx[r]);
        p0[r] = __expf(s0[r] - mx[r]);
        p1[r] = __expf(s1[r] - mx[r]);
        sum[r] = pt[r] + p0[r] + p1[r];
    }
#pragma unroll
    for (int o = 1; o < 16; o <<= 1)
#pragma unroll
        for (int r = 0; r < 4; ++r) sum[r] += __shfl_xor(sum[r], o);
#pragma unroll
    for (int r = 0; r < 4; ++r) {
        const float inv = 1.0f / sum[r];
        pt[r] *= inv; p0[r] *= inv; p1[r] *= inv;
    }

    // ---- tw (f32 out) + sP (bf16, PV A-operand; keys 48-63 zero) ----
#pragma unroll
    for (int r = 0; r < 4; ++r) {
        const int row = g * 4 + r;
        const int tt = t0 + (row >> 3), m = row & 7;
        float* twp = tw + ((((size_t)b * H_ + h) * T_ + tt) * 8 + m) * NKT;
        if ((c >> 3) == th) twp[c & 7] = pt[r];    // temporal cols 0-7 (own half only)
        twp[8 + c]  = p0[r];                        // static cols 8-23
        twp[24 + c] = p1[r];                        // static cols 24-39
        u16* sp = sP + h * 1152 + row * 72;
        sp[c]      = f2b(pt[r]);                    // keys 0-15 (cross-t entries = 0)
        sp[16 + c] = f2b(p0[r]);
        sp[32 + c] = f2b(p1[r]);
        sp[48 + c] = 0;
    }

    // ---- PV: 8 MFMA (A = sP rows, B = sVT d-rows) ----
    f32x4 o4[4] = {{0,0,0,0}, {0,0,0,0}, {0,0,0,0}, {0,0,0,0}};
#pragma unroll
    for (int ks = 0; ks < 2; ++ks) {
        bf16x8 pa = *(const bf16x8*)(sP + h * 1152 + c * 72 + ks * 32 + g * 8);
#pragma unroll
        for (int dt = 0; dt < 4; ++dt) {
            bf16x8 pb = *(const bf16x8*)(sVT + h * 4608 + (dt * 16 + c) * 72 + ks * 32 + g * 8);
            o4[dt] = __builtin_amdgcn_mfma_f32_16x16x32_bf16(pa, pb, o4[dt], 0, 0, 0);
        }
    }
#pragma unroll
    for (int dt = 0; dt < 4; ++dt)
#pragma unroll
        for (int r = 0; r < 4; ++r) {
            const int row = g * 4 + r;
            const int tt = t0 + (row >> 3), m = row & 7;
            qkvt[(((size_t)b * T_ + tt) * 8 + m) * 256 + h * 64 + dt * 16 + c] = f2b(o4[dt][r]);
        }
}

// ---------------- static branch: raw masked scores (MFMA) ----------------
// grid = (33, H, B); per block: Qs_h 32x64 vs 128 keys (or 32 static). 4 waves:
// wave w owns keys w*32..w*32+31 (2 col-tiles). 8 MFMA/wave.
__global__ __launch_bounds__(256) void k_attn_s_scores(
    const u16* __restrict__ Qs, const u16* __restrict__ Kt, const u16* __restrict__ Ks,
    const int* __restrict__ maskT, const int* __restrict__ maskS,
    float* __restrict__ raw)
{
    const int ch = blockIdx.x, h = blockIdx.y, b = blockIdx.z;
    const int nk = (ch < 32) ? 128 : 32;
    const int k0 = ch * 128;
    __shared__ __align__(16) u16 sQ[2 * 32 * 32];      // [ks][q32][32]
    __shared__ __align__(16) u16 sK[2 * 128 * 32];     // [ks][key128][32]
    __shared__ int sM[128];
    const int tid = threadIdx.x;

    {   // Q: 32 rows x 64 d (head range) = 256 uint4
        const int q = tid >> 3, c8 = tid & 7;
        const int ks = c8 >> 2, seg = c8 & 3;
        *(uint4*)(sQ + ks * 1024 + q * 32 + seg * 8) =
            *(const uint4*)(Qs + ((size_t)b * S_ + q) * 256 + h * 64 + c8 * 8);
    }
#pragma unroll
    for (int i = 0; i < 4; ++i) {
        const int fl = tid + i * 256;
        const int key = fl >> 3, c8 = fl & 7;
        const int ks = c8 >> 2, seg = c8 & 3;
        if (key < nk) {
            const u16* src = (ch < 32)
                ? (Kt + ((size_t)b * TM_ + k0 + key) * 256 + h * 64 + c8 * 8)
                : (Ks + ((size_t)b * S_  +      key) * 256 + h * 64 + c8 * 8);
            *(uint4*)(sK + ks * 4096 + key * 32 + seg * 8) = *(const uint4*)src;
        }
    }
    if (tid < nk) sM[tid] = (ch < 32) ? maskT[(size_t)b * TM_ + k0 + tid]
                                      : maskS[b * S_ + tid];
    __syncthreads();

    const int w = tid >> 6, lane = tid & 63;
    if (w * 32 >= nk) return;                       // idle waves for static chunk
    const int c = lane & 15, g = lane >> 4;

    f32x4 acc[2][2] = {{{0,0,0,0}, {0,0,0,0}}, {{0,0,0,0}, {0,0,0,0}}};
#pragma unroll
    for (int ks = 0; ks < 2; ++ks) {
        bf16x8 a0 = *(const bf16x8*)(sQ + ks * 1024 +        c * 32 + g * 8);
        bf16x8 a1 = *(const bf16x8*)(sQ + ks * 1024 + 512 +  c * 32 + g * 8);
        bf16x8 b0 = *(const bf16x8*)(sK + ks * 4096 + (w * 32 +      c) * 32 + g * 8);
        bf16x8 b1 = *(const bf16x8*)(sK + ks * 4096 + (w * 32 + 16 + c) * 32 + g * 8);
        acc[0][0] = __builtin_amdgcn_mfma_f32_16x16x32_bf16(a0, b0, acc[0][0], 0, 0, 0);
        acc[0][1] = __builtin_amdgcn_mfma_f32_16x16x32_bf16(a0, b1, acc[0][1], 0, 0, 0);
        acc[1][0] = __builtin_amdgcn_mfma_f32_16x16x32_bf16(a1, b0, acc[1][0], 0, 0, 0);
        acc[1][1] = __builtin_amdgcn_mfma_f32_16x16x32_bf16(a1, b1, acc[1][1], 0, 0, 0);
    }
#pragma unroll
    for (int rt = 0; rt < 2; ++rt)
#pragma unroll
        for (int ct = 0; ct < 2; ++ct) {
            const int kl = w * 32 + ct * 16 + c;
            const float madd = sM[kl] ? 0.f : -1e30f;
#pragma unroll
            for (int r = 0; r < 4; ++r) {
                const int q = rt * 16 + g * 4 + r;
                raw[(((size_t)b * H_ + h) * S_ + q) * NKS + k0 + kl] =
                    acc[rt][ct][r] * 0.125f + madd;
            }
        }
}

// ---------------- static branch: row softmax ----------------
__global__ __launch_bounds__(256) void k_attn_s_softmax(
    float* __restrict__ raw, float* __restrict__ sw)
{
    const int q = blockIdx.x, h = blockIdx.y, b = blockIdx.z;
    __shared__ float sRow[NKS];
    __shared__ float red[8];
    const int tid = threadIdx.x;
    const size_t base = (((size_t)b * H_ + h) * S_ + q) * NKS;

    float mx = -1e30f;
    for (int i = tid; i < NKS; i += 256) {
        const float v = raw[base + i];
        sRow[i] = v;
        mx = fmaxf(mx, v);
    }
    for (int o = 32; o; o >>= 1) mx = fmaxf(mx, __shfl_xor(mx, o));
    if ((tid & 63) == 0) red[tid >> 6] = mx;
    __syncthreads();
    mx = fmaxf(fmaxf(red[0], red[1]), fmaxf(red[2], red[3]));

    float sum = 0.f;
    for (int i = tid; i < NKS; i += 256) {
        const float e = __expf(sRow[i] - mx);
        sRow[i] = e;
        sum += e;
    }
    for (int o = 32; o; o >>= 1) sum += __shfl_xor(sum, o);
    if ((tid & 63) == 0) red[4 + (tid >> 6)] = sum;
    __syncthreads();
    sum = (red[4] + red[5]) + (red[6] + red[7]);
    const float inv = 1.0f / sum;

    for (int i = tid; i < NKS; i += 256) {
        const float w = sRow[i] * inv;
        raw[base + i] = w;
        sw[base + i]  = w;
    }
}

// ---------------- static branch: split-K PV partials ----------------
__global__ __launch_bounds__(256) void k_attn_s_pv_part(
    const float* __restrict__ w, const u16* __restrict__ Vt, const u16* __restrict__ Vs,
    float* __restrict__ part)
{
    const int ch = blockIdx.x, h = blockIdx.y, b = blockIdx.z;
    const int nk = (ch < 32) ? 128 : 32;
    const int k0 = ch * 128;
    __shared__ float sW[32][132];
    __shared__ __align__(16) u16 sV[128 * 64];
    const int tid = threadIdx.x;

#pragma unroll
    for (int i = 0; i < 4; ++i) {
        const int fl = tid + i * 256;
        const int q = fl >> 5, k4 = fl & 31;
        if (k4 * 4 < nk)
            *(float4*)&sW[q][k4 * 4] =
                *(const float4*)(w + (((size_t)b * H_ + h) * S_ + q) * NKS + k0 + k4 * 4);
    }
#pragma unroll
    for (int i = 0; i < 4; ++i) {
        const int fl = tid + i * 256;
        const int key = fl >> 3, pp = fl & 7;
        if (key < nk) {
            const u16* src = (ch < 32)
                ? (Vt + ((size_t)b * TM_ + k0 + key) * D_ + h * HD_ + pp * 8)
                : (Vs + ((size_t)b * S_  +      key) * D_ + h * HD_ + pp * 8);
            ((uint4*)sV)[fl] = *(const uint4*)src;
        }
    }
    __syncthreads();

    const int d = tid & 63, qg = tid >> 6;
    float acc[8] = {0,0,0,0,0,0,0,0};
    for (int kk = 0; kk < nk; kk += 4) {
        const float v0 = b2f(sV[(kk + 0) * 64 + d]);
        const float v1 = b2f(sV[(kk + 1) * 64 + d]);
        const float v2 = b2f(sV[(kk + 2) * 64 + d]);
        const float v3 = b2f(sV[(kk + 3) * 64 + d]);
#pragma unroll
        for (int j = 0; j < 8; ++j) {
            const float4 wv = *(const float4*)&sW[qg * 8 + j][kk];
            acc[j] += wv.x * v0 + wv.y * v1 + wv.z * v2 + wv.w * v3;
        }
    }

    float* pb = part + (((size_t)ch * B_ + b) * H_ + h) * 2048;
#pragma unroll
    for (int j = 0; j < 8; ++j)
        pb[(qg * 8 + j) * 64 + d] = acc[j];
}

// ---------------- static branch: PV reduce ----------------
__global__ __launch_bounds__(256) void k_attn_s_pv_red(
    const float* __restrict__ part, u16* __restrict__ qkvs)
{
    const int h = blockIdx.x, b = blockIdx.y;
    const int tid = threadIdx.x;
    for (int i = tid; i < 2048; i += 256) {
        float s = 0.f;
#pragma unroll
        for (int c = 0; c < 33; ++c)
            s += part[(((size_t)c * B_ + b) * H_ + h) * 2048 + i];
        const int q = i >> 6, d = i & 63;
        qkvs[((size_t)b * S_ + q) * D_ + h * HD_ + d] = f2b(s);
    }
}

// ---------------- launch ----------------
extern "C" void kernel_launch(void* const* d_in, const int* in_sizes, int n_in,
                              void* d_out, int out_size, void* d_ws, size_t ws_size,
                              hipStream_t stream)
{
    const float* q_t = (const float*)d_in[0];
    const float* q_s = (const float*)d_in[1];
    const float* k_t = (const float*)d_in[2];
    const float* v_t = (const float*)d_in[3];
    const float* k_s = (const float*)d_in[4];
    const float* v_s = (const float*)d_in[5];
    const float* q_w = (const float*)d_in[6];
    const float* q_b = (const float*)d_in[7];
    const float* k_w = (const float*)d_in[8];
    const float* k_b = (const float*)d_in[9];
    const float* v_w = (const float*)d_in[10];
    const float* v_b = (const float*)d_in[11];
    const float* o_w = (const float*)d_in[12];
    const float* o_b = (const float*)d_in[13];
    const int* maskT = (const int*)d_in[14];
    // d_in[15] = mask_fcst: unused by the reference
    const int* maskS = (const int*)d_in[16];
    float* out = (float*)d_out;

    char* ws = (char*)d_ws;
    u16*   Kt   = (u16*)(ws + 0);
    u16*   Vt   = (u16*)(ws + 33554432);
    u16*   QKVt = (u16*)(ws + 67108864);
    float* part = (float*)(ws + 67108864);   // aliases QKVt (dead after out_t GEMM)
    u16*   Qs   = (u16*)(ws + 100663296);
    u16*   Ks   = (u16*)(ws + 100925440);
    u16*   Vs   = (u16*)(ws + 101187584);
    u16*   QKVs = (u16*)(ws + 101449728);
    u16*   Qt   = (u16*)(ws + 101711872);
    float* raw  = (float*)(ws + 101711872);  // aliases Qt (dead before scores run)
    if (ws_size < 135528448) return;         // required workspace

    float* out_t = out;                 // [B,T,M,D]
    float* out_s = out + 16777216;      // [B,S,D]
    float* tw    = out + 16908288;      // [B,H,T,M,40]
    float* sw    = out + 27394048;      // [B,H,S,4128]

    const dim3 blk(256);
    k_gemm_m<0,0><<<dim3(1024), blk, 0, stream>>>(q_t, q_w, q_b, Qt);
    k_gemm_m<0,0><<<dim3(1024), blk, 0, stream>>>(k_t, k_w, k_b, Kt);
    k_gemm_m<0,0><<<dim3(1024), blk, 0, stream>>>(v_t, v_w, v_b, Vt);
    k_gemm_m<0,0><<<dim3(8),    blk, 0, stream>>>(q_s, q_w, q_b, Qs);
    k_gemm_m<0,0><<<dim3(8),    blk, 0, stream>>>(k_s, k_w, k_b, Ks);
    k_gemm_m<0,0><<<dim3(8),    blk, 0, stream>>>(v_s, v_w, v_b, Vs);

    k_attn_t<<<dim3(256, 16), blk, 0, stream>>>(Qt, Kt, Vt, Ks, Vs, maskT, maskS, tw, QKVt);

    // out_t projection FIRST: frees QKVt so PV partials can alias it.
    k_gemm_m<1,1><<<dim3(1024), blk, 0, stream>>>(QKVt, o_w, o_b, out_t);

    k_attn_s_scores<<<dim3(33, 4, 16), blk, 0, stream>>>(Qs, Kt, Ks, maskT, maskS, raw);
    k_attn_s_softmax<<<dim3(32, 4, 16), blk, 0, stream>>>(raw, sw);
    k_attn_s_pv_part<<<dim3(33, 4, 16), blk, 0, stream>>>(raw, Vt, Vs, part);
    k_attn_s_pv_red<<<dim3(4, 16), blk, 0, stream>>>(part, QKVs);

    k_gemm_m<1,1><<<dim3(8),    blk, 0, stream>>>(QKVs, o_w, o_b, out_s);
}

// Round 8
// 284.337 us; speedup vs baseline: 3.5653x; 1.1608x over previous
//
#include <hip/hip_runtime.h>

// ---------------- constants ----------------
#define B_   16
#define T_   512
#define M_   8
#define S_   32
#define D_   256
#define H_   4
#define HD_  64
#define TM_  4096      // T*M
#define NKT  40        // M+S
#define NKS  4128      // T*M+S

typedef unsigned short u16;
typedef __attribute__((ext_vector_type(8))) short bf16x8;
typedef __attribute__((ext_vector_type(4))) float f32x4;

// ---------------- bf16 helpers ----------------
__device__ __forceinline__ u16 f2b(float f) {
    union { float f; unsigned u; } v; v.f = f;
    unsigned r = v.u + 0x7FFF + ((v.u >> 16) & 1);   // RNE
    return (u16)(r >> 16);
}
__device__ __forceinline__ float blo(unsigned u) {
    union { unsigned i; float f; } v; v.i = u << 16; return v.f;
}
__device__ __forceinline__ float bhi(unsigned u) {
    union { unsigned i; float f; } v; v.i = u & 0xFFFF0000u; return v.f;
}
__device__ __forceinline__ float b2f(u16 u) {
    union { unsigned i; float f; } v; v.i = ((unsigned)u) << 16; return v.f;
}
__device__ __forceinline__ unsigned pack2(float lo, float hi) {
    return (unsigned)f2b(lo) | ((unsigned)f2b(hi) << 16);
}
__device__ __forceinline__ uint4 cvt8(float4 a, float4 b) {
    uint4 r;
    r.x = pack2(a.x, a.y); r.y = pack2(a.z, a.w);
    r.z = pack2(b.x, b.y); r.w = pack2(b.z, b.w);
    return r;
}

// ---------------- GEMM body: Y[r][c] = X[r]·W[c] + bias[c] ----------------
// 64 rows x 256 cols per block, BK=32, 4 waves. Double-buffered LDS, ONE
// barrier per K-step: loads for tile k+1 issue BEFORE the barrier/MFMAs of
// tile k; LDS write goes to buf^1 (safe: write(buf b,k+2) separated from
// read(buf b,k) by barrier(k+1)).
template<int XBF, int OUTF32>
__device__ __forceinline__ void gemm_body(const void* __restrict__ Xv,
                                          const float* __restrict__ W,
                                          const float* __restrict__ bias,
                                          void* __restrict__ Yv,
                                          int bx, u16* sA, u16* sB)
{
    const int tid = threadIdx.x;
    const size_t r0 = (size_t)bx * 64;
    const int wave = tid >> 6, lane = tid & 63;
    const int rbase = lane & 15, kseg = (lane >> 4) * 8;
    const int arow = tid >> 2, aseg = tid & 3;

    f32x4 acc[4][4];
#pragma unroll
    for (int i = 0; i < 4; ++i)
#pragma unroll
        for (int j = 0; j < 4; ++j) acc[i][j] = (f32x4){0, 0, 0, 0};

#define LOAD_A(k0, dst)                                                          \
    if (XBF) dst = *(const uint4*)((const u16*)Xv + (r0 + arow) * 256 + (k0) + aseg * 8); \
    else {                                                                       \
        const float* gA = (const float*)Xv + (r0 + arow) * 256 + (k0) + aseg * 8; \
        dst = cvt8(*(const float4*)gA, *(const float4*)(gA + 4));                \
    }
#define LOAD_B(k0, dst)                                                          \
    _Pragma("unroll")                                                            \
    for (int i = 0; i < 4; ++i) {                                                \
        const int s = i * 256 + tid;                                             \
        const float* gB = W + (size_t)(s >> 2) * 256 + (k0) + (s & 3) * 8;       \
        dst[i] = cvt8(*(const float4*)gB, *(const float4*)(gB + 4));             \
    }

    {   // prologue: stage tile 0 into buf 0
        uint4 aC, bC[4];
        LOAD_A(0, aC)
        LOAD_B(0, bC)
        *(uint4*)(sA + tid * 8) = aC;
#pragma unroll
        for (int i = 0; i < 4; ++i)
            *(uint4*)(sB + (i * 256 + tid) * 8) = bC[i];
    }

    for (int k = 0; k < 8; ++k) {
        const int cur = k & 1;
        uint4 aN, bN[4];
        if (k < 7) {
            LOAD_A((k + 1) * 32, aN)
            LOAD_B((k + 1) * 32, bN)
        }
        __syncthreads();
        const u16* A = sA + cur * 2048;
        const u16* Bb = sB + cur * 8192;
        bf16x8 a[4], b[4];
#pragma unroll
        for (int f = 0; f < 4; ++f)
            a[f] = *(const bf16x8*)(A + (f * 16 + rbase) * 32 + kseg);
#pragma unroll
        for (int f = 0; f < 4; ++f)
            b[f] = *(const bf16x8*)(Bb + (wave * 64 + f * 16 + rbase) * 32 + kseg);
#pragma unroll
        for (int rf = 0; rf < 4; ++rf)
#pragma unroll
            for (int cf = 0; cf < 4; ++cf)
                acc[rf][cf] = __builtin_amdgcn_mfma_f32_16x16x32_bf16(
                    a[rf], b[cf], acc[rf][cf], 0, 0, 0);
        if (k < 7) {
            u16* A1 = sA + (cur ^ 1) * 2048;
            u16* B1 = sB + (cur ^ 1) * 8192;
            *(uint4*)(A1 + tid * 8) = aN;
#pragma unroll
            for (int i = 0; i < 4; ++i)
                *(uint4*)(B1 + (i * 256 + tid) * 8) = bN[i];
        }
    }
#undef LOAD_A
#undef LOAD_B

    // C/D mapping (bit-verified vs VALU GEMM rounds 2/3): col=lane&15, row=(lane>>4)*4+reg
    const int orow = (lane >> 4) * 4, ocol = lane & 15;
#pragma unroll
    for (int cf = 0; cf < 4; ++cf) {
        const int col = wave * 64 + cf * 16 + ocol;
        const float bv = bias[col];
#pragma unroll
        for (int rf = 0; rf < 4; ++rf)
#pragma unroll
            for (int r = 0; r < 4; ++r) {
                const size_t row = r0 + rf * 16 + orow + r;
                const float y = acc[rf][cf][r] + bv;
                if (OUTF32) ((float*)Yv)[row * 256 + col] = y;
                else        ((u16*) Yv)[row * 256 + col] = f2b(y);
            }
    }
}

template<int XBF, int OUTF32>
__global__ __launch_bounds__(256) void k_gemm_m(const void* __restrict__ Xv,
                                                const float* __restrict__ W,
                                                const float* __restrict__ bias,
                                                void* __restrict__ Yv)
{
    __shared__ __align__(16) u16 sA[2 * 2048];
    __shared__ __align__(16) u16 sB[2 * 8192];
    gemm_body<XBF, OUTF32>(Xv, W, bias, Yv, blockIdx.x, sA, sB);
}

// Fused 3-projection GEMM (q/k/v share structure): blockIdx.y selects tensor.
__global__ __launch_bounds__(256) void k_gemm_qkv(
    const float* __restrict__ X0, const float* __restrict__ X1, const float* __restrict__ X2,
    const float* __restrict__ W0, const float* __restrict__ W1, const float* __restrict__ W2,
    const float* __restrict__ b0, const float* __restrict__ b1, const float* __restrict__ b2,
    u16* __restrict__ Y0, u16* __restrict__ Y1, u16* __restrict__ Y2)
{
    __shared__ __align__(16) u16 sA[2 * 2048];
    __shared__ __align__(16) u16 sB[2 * 8192];
    const int sel = blockIdx.y;
    const float* X = sel == 0 ? X0 : sel == 1 ? X1 : X2;
    const float* W = sel == 0 ? W0 : sel == 1 ? W1 : W2;
    const float* bb = sel == 0 ? b0 : sel == 1 ? b1 : b2;
    u16* Y = sel == 0 ? Y0 : sel == 1 ? Y1 : Y2;
    gemm_body<0, 0>(X, W, bb, Y, blockIdx.x, sA, sB);
}

// ---------------- temporal attention (MFMA): one block per (t-pair, b) --------
__global__ __launch_bounds__(256) void k_attn_t(
    const u16* __restrict__ Qt, const u16* __restrict__ Kt, const u16* __restrict__ Vt,
    const u16* __restrict__ Ks, const u16* __restrict__ Vs,
    const int* __restrict__ maskT, const int* __restrict__ maskS,
    float* __restrict__ tw, u16* __restrict__ qkvt)
{
    const int tp = blockIdx.x, b = blockIdx.y;
    const int t0 = tp * 2;
    __shared__ __align__(16) u16 sQ [4 * 2 * 16 * 32];   // [h][ks][row16][32]
    __shared__ __align__(16) u16 sKT[4 * 2 * 16 * 32];
    __shared__ __align__(16) u16 sKS[4 * 2 * 32 * 32];
    __shared__ __align__(16) u16 sVT[4 * 64 * 72];       // [h][d64][key72], keys48-63=0
    __shared__ __align__(16) u16 sP [4 * 16 * 72];
    __shared__ int smT[2][8];
    __shared__ int smS[32];
    const int tid = threadIdx.x;

#pragma unroll
    for (int i = 0; i < 2; ++i) {
        const int fl = tid + i * 256;
        const int r = fl >> 5, c32 = fl & 31;
        const int h = c32 >> 3, ks = (c32 >> 2) & 1, seg = c32 & 3;
        const size_t src = (((size_t)b * T_ + t0 + (r >> 3)) * 8 + (r & 7)) * 256 + c32 * 8;
        const int dst = h * 1024 + ks * 512 + r * 32 + seg * 8;
        *(uint4*)(sQ  + dst) = *(const uint4*)(Qt + src);
        *(uint4*)(sKT + dst) = *(const uint4*)(Kt + src);
    }
#pragma unroll
    for (int i = 0; i < 4; ++i) {
        const int fl = tid + i * 256;
        const int r = fl >> 5, c32 = fl & 31;
        const int h = c32 >> 3, ks = (c32 >> 2) & 1, seg = c32 & 3;
        *(uint4*)(sKS + h * 2048 + ks * 1024 + r * 32 + seg * 8) =
            *(const uint4*)(Ks + ((size_t)b * S_ + r) * 256 + c32 * 8);
    }
    {
        const int key = tid & 63, dg = tid >> 6;
        const u16* vrow = nullptr;
        if (key < 16)      vrow = Vt + (((size_t)b * T_ + t0 + (key >> 3)) * 8 + (key & 7)) * 256;
        else if (key < 48) vrow = Vs + ((size_t)b * S_ + (key - 16)) * 256;
#pragma unroll
        for (int i = 0; i < 8; ++i) {
            const int dseg = dg * 8 + i;
            uint4 v = {0, 0, 0, 0};
            if (vrow) v = *(const uint4*)(vrow + dseg * 8);
            const int h = dseg >> 3, dl0 = (dseg & 7) * 8;
            const u16* pv = (const u16*)&v;
#pragma unroll
            for (int j = 0; j < 8; ++j)
                sVT[h * 4608 + (dl0 + j) * 72 + key] = pv[j];
        }
    }
    if (tid < 16) smT[tid >> 3][tid & 7] =
        maskT[((size_t)b * T_ + t0 + (tid >> 3)) * 8 + (tid & 7)];
    if (tid < 32) smS[tid] = maskS[b * S_ + tid];
    __syncthreads();

    const int h = tid >> 6, lane = tid & 63;
    const int c = lane & 15, g = lane >> 4, th = g >> 1;

    f32x4 at = {0,0,0,0}, as0 = {0,0,0,0}, as1 = {0,0,0,0};
#pragma unroll
    for (int ks = 0; ks < 2; ++ks) {
        bf16x8 aq = *(const bf16x8*)(sQ  + h * 1024 + ks * 512 + c * 32 + g * 8);
        bf16x8 bt = *(const bf16x8*)(sKT + h * 1024 + ks * 512 + c * 32 + g * 8);
        bf16x8 b0 = *(const bf16x8*)(sKS + h * 2048 + ks * 1024 + c * 32 + g * 8);
        bf16x8 b1 = *(const bf16x8*)(sKS + h * 2048 + ks * 1024 + 512 + c * 32 + g * 8);
        at  = __builtin_amdgcn_mfma_f32_16x16x32_bf16(aq, bt, at, 0, 0, 0);
        as0 = __builtin_amdgcn_mfma_f32_16x16x32_bf16(aq, b0, as0, 0, 0, 0);
        as1 = __builtin_amdgcn_mfma_f32_16x16x32_bf16(aq, b1, as1, 0, 0, 0);
    }

    const int vt = ((c >> 3) == th) ? smT[th][c & 7] : 0;
    const int v0 = smS[c], v1 = smS[16 + c];
    float st[4], s0[4], s1[4], mx[4];
#pragma unroll
    for (int r = 0; r < 4; ++r) {
        st[r] = vt ? at[r]  * 0.125f : -1e30f;
        s0[r] = v0 ? as0[r] * 0.125f : -1e30f;
        s1[r] = v1 ? as1[r] * 0.125f : -1e30f;
        mx[r] = fmaxf(fmaxf(st[r], s0[r]), s1[r]);
    }
#pragma unroll
    for (int o = 1; o < 16; o <<= 1)
#pragma unroll
        for (int r = 0; r < 4; ++r) mx[r] = fmaxf(mx[r], __shfl_xor(mx[r], o));
    float pt[4], p0[4], p1[4], sum[4];
#pragma unroll
    for (int r = 0; r < 4; ++r) {
        pt[r] = __expf(st[r] - mx[r]);
        p0[r] = __expf(s0[r] - mx[r]);
        p1[r] = __expf(s1[r] - mx[r]);
        sum[r] = pt[r] + p0[r] + p1[r];
    }
#pragma unroll
    for (int o = 1; o < 16; o <<= 1)
#pragma unroll
        for (int r = 0; r < 4; ++r) sum[r] += __shfl_xor(sum[r], o);
#pragma unroll
    for (int r = 0; r < 4; ++r) {
        const float inv = 1.0f / sum[r];
        pt[r] *= inv; p0[r] *= inv; p1[r] *= inv;
    }

#pragma unroll
    for (int r = 0; r < 4; ++r) {
        const int row = g * 4 + r;
        const int tt = t0 + (row >> 3), m = row & 7;
        float* twp = tw + ((((size_t)b * H_ + h) * T_ + tt) * 8 + m) * NKT;
        if ((c >> 3) == th) twp[c & 7] = pt[r];
        twp[8 + c]  = p0[r];
        twp[24 + c] = p1[r];
        u16* sp = sP + h * 1152 + row * 72;
        sp[c]      = f2b(pt[r]);
        sp[16 + c] = f2b(p0[r]);
        sp[32 + c] = f2b(p1[r]);
        sp[48 + c] = 0;
    }

    f32x4 o4[4] = {{0,0,0,0}, {0,0,0,0}, {0,0,0,0}, {0,0,0,0}};
#pragma unroll
    for (int ks = 0; ks < 2; ++ks) {
        bf16x8 pa = *(const bf16x8*)(sP + h * 1152 + c * 72 + ks * 32 + g * 8);
#pragma unroll
        for (int dt = 0; dt < 4; ++dt) {
            bf16x8 pb = *(const bf16x8*)(sVT + h * 4608 + (dt * 16 + c) * 72 + ks * 32 + g * 8);
            o4[dt] = __builtin_amdgcn_mfma_f32_16x16x32_bf16(pa, pb, o4[dt], 0, 0, 0);
        }
    }
#pragma unroll
    for (int dt = 0; dt < 4; ++dt)
#pragma unroll
        for (int r = 0; r < 4; ++r) {
            const int row = g * 4 + r;
            const int tt = t0 + (row >> 3), m = row & 7;
            qkvt[(((size_t)b * T_ + tt) * 8 + m) * 256 + h * 64 + dt * 16 + c] = f2b(o4[dt][r]);
        }
}

// ---------------- static branch: raw masked scores (MFMA) ----------------
__global__ __launch_bounds__(256) void k_attn_s_scores(
    const u16* __restrict__ Qs, const u16* __restrict__ Kt, const u16* __restrict__ Ks,
    const int* __restrict__ maskT, const int* __restrict__ maskS,
    float* __restrict__ raw)
{
    const int ch = blockIdx.x, h = blockIdx.y, b = blockIdx.z;
    const int nk = (ch < 32) ? 128 : 32;
    const int k0 = ch * 128;
    __shared__ __align__(16) u16 sQ[2 * 32 * 32];
    __shared__ __align__(16) u16 sK[2 * 128 * 32];
    __shared__ int sM[128];
    const int tid = threadIdx.x;

    {   const int q = tid >> 3, c8 = tid & 7;
        const int ks = c8 >> 2, seg = c8 & 3;
        *(uint4*)(sQ + ks * 1024 + q * 32 + seg * 8) =
            *(const uint4*)(Qs + ((size_t)b * S_ + q) * 256 + h * 64 + c8 * 8);
    }
#pragma unroll
    for (int i = 0; i < 4; ++i) {
        const int fl = tid + i * 256;
        const int key = fl >> 3, c8 = fl & 7;
        const int ks = c8 >> 2, seg = c8 & 3;
        if (key < nk) {
            const u16* src = (ch < 32)
                ? (Kt + ((size_t)b * TM_ + k0 + key) * 256 + h * 64 + c8 * 8)
                : (Ks + ((size_t)b * S_  +      key) * 256 + h * 64 + c8 * 8);
            *(uint4*)(sK + ks * 4096 + key * 32 + seg * 8) = *(const uint4*)src;
        }
    }
    if (tid < nk) sM[tid] = (ch < 32) ? maskT[(size_t)b * TM_ + k0 + tid]
                                      : maskS[b * S_ + tid];
    __syncthreads();

    const int w = tid >> 6, lane = tid & 63;
    if (w * 32 >= nk) return;
    const int c = lane & 15, g = lane >> 4;

    f32x4 acc[2][2] = {{{0,0,0,0}, {0,0,0,0}}, {{0,0,0,0}, {0,0,0,0}}};
#pragma unroll
    for (int ks = 0; ks < 2; ++ks) {
        bf16x8 a0 = *(const bf16x8*)(sQ + ks * 1024 +        c * 32 + g * 8);
        bf16x8 a1 = *(const bf16x8*)(sQ + ks * 1024 + 512 +  c * 32 + g * 8);
        bf16x8 b0 = *(const bf16x8*)(sK + ks * 4096 + (w * 32 +      c) * 32 + g * 8);
        bf16x8 b1 = *(const bf16x8*)(sK + ks * 4096 + (w * 32 + 16 + c) * 32 + g * 8);
        acc[0][0] = __builtin_amdgcn_mfma_f32_16x16x32_bf16(a0, b0, acc[0][0], 0, 0, 0);
        acc[0][1] = __builtin_amdgcn_mfma_f32_16x16x32_bf16(a0, b1, acc[0][1], 0, 0, 0);
        acc[1][0] = __builtin_amdgcn_mfma_f32_16x16x32_bf16(a1, b0, acc[1][0], 0, 0, 0);
        acc[1][1] = __builtin_amdgcn_mfma_f32_16x16x32_bf16(a1, b1, acc[1][1], 0, 0, 0);
    }
#pragma unroll
    for (int rt = 0; rt < 2; ++rt)
#pragma unroll
        for (int ct = 0; ct < 2; ++ct) {
            const int kl = w * 32 + ct * 16 + c;
            const float madd = sM[kl] ? 0.f : -1e30f;
#pragma unroll
            for (int r = 0; r < 4; ++r) {
                const int q = rt * 16 + g * 4 + r;
                raw[(((size_t)b * H_ + h) * S_ + q) * NKS + k0 + kl] =
                    acc[rt][ct][r] * 0.125f + madd;
            }
        }
}

// ---------------- static branch: row softmax (reads raw, writes sw only) -------
__global__ __launch_bounds__(256) void k_attn_s_softmax(
    const float* __restrict__ raw, float* __restrict__ sw)
{
    const int q = blockIdx.x, h = blockIdx.y, b = blockIdx.z;
    __shared__ float sRow[NKS];
    __shared__ float red[8];
    const int tid = threadIdx.x;
    const size_t base = (((size_t)b * H_ + h) * S_ + q) * NKS;

    float mx = -1e30f;
    for (int i = tid; i < NKS; i += 256) {
        const float v = raw[base + i];
        sRow[i] = v;
        mx = fmaxf(mx, v);
    }
    for (int o = 32; o; o >>= 1) mx = fmaxf(mx, __shfl_xor(mx, o));
    if ((tid & 63) == 0) red[tid >> 6] = mx;
    __syncthreads();
    mx = fmaxf(fmaxf(red[0], red[1]), fmaxf(red[2], red[3]));

    float sum = 0.f;
    for (int i = tid; i < NKS; i += 256) {
        const float e = __expf(sRow[i] - mx);
        sRow[i] = e;
        sum += e;
    }
    for (int o = 32; o; o >>= 1) sum += __shfl_xor(sum, o);
    if ((tid & 63) == 0) red[4 + (tid >> 6)] = sum;
    __syncthreads();
    sum = (red[4] + red[5]) + (red[6] + red[7]);
    const float inv = 1.0f / sum;

    for (int i = tid; i < NKS; i += 256)
        sw[base + i] = sRow[i] * inv;           // single copy; pv reads sw
}

// ---------------- static branch: split-K PV partials (reads sw) ----------------
__global__ __launch_bounds__(256) void k_attn_s_pv_part(
    const float* __restrict__ w, const u16* __restrict__ Vt, const u16* __restrict__ Vs,
    float* __restrict__ part)
{
    const int ch = blockIdx.x, h = blockIdx.y, b = blockIdx.z;
    const int nk = (ch < 32) ? 128 : 32;
    const int k0 = ch * 128;
    __shared__ float sW[32][132];
    __shared__ __align__(16) u16 sV[128 * 64];
    const int tid = threadIdx.x;

#pragma unroll
    for (int i = 0; i < 4; ++i) {
        const int fl = tid + i * 256;
        const int q = fl >> 5, k4 = fl & 31;
        if (k4 * 4 < nk)
            *(float4*)&sW[q][k4 * 4] =
                *(const float4*)(w + (((size_t)b * H_ + h) * S_ + q) * NKS + k0 + k4 * 4);
    }
#pragma unroll
    for (int i = 0; i < 4; ++i) {
        const int fl = tid + i * 256;
        const int key = fl >> 3, pp = fl & 7;
        if (key < nk) {
            const u16* src = (ch < 32)
                ? (Vt + ((size_t)b * TM_ + k0 + key) * D_ + h * HD_ + pp * 8)
                : (Vs + ((size_t)b * S_  +      key) * D_ + h * HD_ + pp * 8);
            ((uint4*)sV)[fl] = *(const uint4*)src;
        }
    }
    __syncthreads();

    const int d = tid & 63, qg = tid >> 6;
    float acc[8] = {0,0,0,0,0,0,0,0};
    for (int kk = 0; kk < nk; kk += 4) {
        const float v0 = b2f(sV[(kk + 0) * 64 + d]);
        const float v1 = b2f(sV[(kk + 1) * 64 + d]);
        const float v2 = b2f(sV[(kk + 2) * 64 + d]);
        const float v3 = b2f(sV[(kk + 3) * 64 + d]);
#pragma unroll
        for (int j = 0; j < 8; ++j) {
            const float4 wv = *(const float4*)&sW[qg * 8 + j][kk];
            acc[j] += wv.x * v0 + wv.y * v1 + wv.z * v2 + wv.w * v3;
        }
    }

    float* pb = part + (((size_t)ch * B_ + b) * H_ + h) * 2048;
#pragma unroll
    for (int j = 0; j < 8; ++j)
        pb[(qg * 8 + j) * 64 + d] = acc[j];
}

// ---------------- static branch: PV reduce ----------------
__global__ __launch_bounds__(256) void k_attn_s_pv_red(
    const float* __restrict__ part, u16* __restrict__ qkvs)
{
    const int h = blockIdx.x, b = blockIdx.y;
    const int tid = threadIdx.x;
    for (int i = tid; i < 2048; i += 256) {
        float s = 0.f;
#pragma unroll
        for (int c = 0; c < 33; ++c)
            s += part[(((size_t)c * B_ + b) * H_ + h) * 2048 + i];
        const int q = i >> 6, d = i & 63;
        qkvs[((size_t)b * S_ + q) * D_ + h * HD_ + d] = f2b(s);
    }
}

// ---------------- launch ----------------
extern "C" void kernel_launch(void* const* d_in, const int* in_sizes, int n_in,
                              void* d_out, int out_size, void* d_ws, size_t ws_size,
                              hipStream_t stream)
{
    const float* q_t = (const float*)d_in[0];
    const float* q_s = (const float*)d_in[1];
    const float* k_t = (const float*)d_in[2];
    const float* v_t = (const float*)d_in[3];
    const float* k_s = (const float*)d_in[4];
    const float* v_s = (const float*)d_in[5];
    const float* q_w = (const float*)d_in[6];
    const float* q_b = (const float*)d_in[7];
    const float* k_w = (const float*)d_in[8];
    const float* k_b = (const float*)d_in[9];
    const float* v_w = (const float*)d_in[10];
    const float* v_b = (const float*)d_in[11];
    const float* o_w = (const float*)d_in[12];
    const float* o_b = (const float*)d_in[13];
    const int* maskT = (const int*)d_in[14];
    // d_in[15] = mask_fcst: unused by the reference
    const int* maskS = (const int*)d_in[16];
    float* out = (float*)d_out;

    char* ws = (char*)d_ws;
    u16*   Kt   = (u16*)(ws + 0);
    u16*   Vt   = (u16*)(ws + 33554432);
    u16*   QKVt = (u16*)(ws + 67108864);
    float* part = (float*)(ws + 67108864);   // aliases QKVt (dead after out_t GEMM)
    u16*   Qs   = (u16*)(ws + 100663296);
    u16*   Ks   = (u16*)(ws + 100925440);
    u16*   Vs   = (u16*)(ws + 101187584);
    u16*   QKVs = (u16*)(ws + 101449728);
    u16*   Qt   = (u16*)(ws + 101711872);
    float* raw  = (float*)(ws + 101711872);  // aliases Qt (dead before scores run)
    if (ws_size < 135528448) return;         // required workspace

    float* out_t = out;                 // [B,T,M,D]
    float* out_s = out + 16777216;      // [B,S,D]
    float* tw    = out + 16908288;      // [B,H,T,M,40]
    float* sw    = out + 27394048;      // [B,H,S,4128]

    const dim3 blk(256);
    k_gemm_qkv<<<dim3(1024, 3), blk, 0, stream>>>(q_t, k_t, v_t, q_w, k_w, v_w,
                                                  q_b, k_b, v_b, Qt, Kt, Vt);
    k_gemm_qkv<<<dim3(8, 3),    blk, 0, stream>>>(q_s, k_s, v_s, q_w, k_w, v_w,
                                                  q_b, k_b, v_b, Qs, Ks, Vs);

    k_attn_t<<<dim3(256, 16), blk, 0, stream>>>(Qt, Kt, Vt, Ks, Vs, maskT, maskS, tw, QKVt);

    // out_t projection FIRST: frees QKVt so PV partials can alias it.
    k_gemm_m<1,1><<<dim3(1024), blk, 0, stream>>>(QKVt, o_w, o_b, out_t);

    k_attn_s_scores<<<dim3(33, 4, 16), blk, 0, stream>>>(Qs, Kt, Ks, maskT, maskS, raw);
    k_attn_s_softmax<<<dim3(32, 4, 16), blk, 0, stream>>>(raw, sw);
    k_attn_s_pv_part<<<dim3(33, 4, 16), blk, 0, stream>>>(sw, Vt, Vs, part);
    k_attn_s_pv_red<<<dim3(4, 16), blk, 0, stream>>>(part, QKVs);

    k_gemm_m<1,1><<<dim3(8),    blk, 0, stream>>>(QKVs, o_w, o_b, out_s);
}

// Round 9
// 257.511 us; speedup vs baseline: 3.9367x; 1.1042x over previous
//
#include <hip/hip_runtime.h>

// ---------------- constants ----------------
#define B_   16
#define T_   512
#define M_   8
#define S_   32
#define D_   256
#define H_   4
#define HD_  64
#define TM_  4096      // T*M
#define NKT  40        // M+S
#define NKS  4128      // T*M+S

typedef unsigned short u16;
typedef __attribute__((ext_vector_type(8))) short bf16x8;
typedef __attribute__((ext_vector_type(4))) float f32x4;

// ---------------- bf16 helpers ----------------
__device__ __forceinline__ u16 f2b(float f) {
    union { float f; unsigned u; } v; v.f = f;
    unsigned r = v.u + 0x7FFF + ((v.u >> 16) & 1);   // RNE
    return (u16)(r >> 16);
}
__device__ __forceinline__ float blo(unsigned u) {
    union { unsigned i; float f; } v; v.i = u << 16; return v.f;
}
__device__ __forceinline__ float bhi(unsigned u) {
    union { unsigned i; float f; } v; v.i = u & 0xFFFF0000u; return v.f;
}
__device__ __forceinline__ float b2f(u16 u) {
    union { unsigned i; float f; } v; v.i = ((unsigned)u) << 16; return v.f;
}
__device__ __forceinline__ unsigned pack2(float lo, float hi) {
    return (unsigned)f2b(lo) | ((unsigned)f2b(hi) << 16);
}
__device__ __forceinline__ uint4 cvt8(float4 a, float4 b) {
    uint4 r;
    r.x = pack2(a.x, a.y); r.y = pack2(a.z, a.w);
    r.z = pack2(b.x, b.y); r.w = pack2(b.z, b.w);
    return r;
}

#define GLL16(g, l) __builtin_amdgcn_global_load_lds( \
    (const __attribute__((address_space(1))) void*)(g), \
    (__attribute__((address_space(3))) void*)(l), 16, 0, 0)

// ---------------- weight pre-convert: f32 -> bf16 (RNE, bit-identical) --------
// grid (32, nsel); each thread converts 8 elems of a 256x256 W.
__global__ __launch_bounds__(256) void k_cvt_w(const float* __restrict__ W0,
                                               const float* __restrict__ W1,
                                               const float* __restrict__ W2,
                                               u16* __restrict__ dst)
{
    const int sel = blockIdx.y;
    const float* W = sel == 0 ? W0 : sel == 1 ? W1 : W2;
    u16* d = dst + sel * 65536;
    const int i0 = (blockIdx.x * 256 + threadIdx.x) * 8;
    const float4 a = *(const float4*)(W + i0);
    const float4 b = *(const float4*)(W + i0 + 4);
    *(uint4*)(d + i0) = cvt8(a, b);
}

// ---------------- GEMM body: Y[r][c] = X[r]·Wb[c] + bias[c] ----------------
// 64 rows x 256 cols per block, BK=32, 4 waves. Wb is PRE-CONVERTED bf16.
// B (and A when XBF) staged via global_load_lds (async DMA, no VALU).
// Double-buffered, ONE barrier per K-step; stage-issue AFTER the barrier
// (all waves have finished reading the target buffer), drained by the next
// barrier. bf16 output goes through an LDS transpose for coalesced stores.
template<int XBF, int OUTF32>
__device__ __forceinline__ void gemm_body(const void* __restrict__ Xv,
                                          const u16* __restrict__ Wb,
                                          const float* __restrict__ bias,
                                          void* __restrict__ Yv,
                                          int bx, u16* smem)
{
    u16* sA = smem;              // 2 x 2048 u16 (two 4 KB buffers)
    u16* sB = smem + 4096;       // 2 x 8192 u16 (two 16 KB buffers)
    const int tid = threadIdx.x;
    const size_t r0 = (size_t)bx * 64;
    const int wave = tid >> 6, lane = tid & 63;
    const int rbase = lane & 15, kseg = (lane >> 4) * 8;
    const int arow = tid >> 2, aseg = tid & 3;

    f32x4 acc[4][4];
#pragma unroll
    for (int i = 0; i < 4; ++i)
#pragma unroll
        for (int j = 0; j < 4; ++j) acc[i][j] = (f32x4){0, 0, 0, 0};

#define LOAD_A_F32(k0, dst) {                                                    \
        const float* gA = (const float*)Xv + (r0 + arow) * 256 + (k0) + aseg * 8; \
        dst = cvt8(*(const float4*)gA, *(const float4*)(gA + 4));                \
    }
#define STAGE_B_GLL(k0, bi)                                                      \
    _Pragma("unroll")                                                            \
    for (int i = 0; i < 4; ++i) {                                                \
        const int s = i * 256 + tid;                                             \
        GLL16(Wb + (size_t)(s >> 2) * 256 + (k0) + (s & 3) * 8,                  \
              sB + (bi) * 8192 + (i * 256 + wave * 64) * 8);                     \
    }
#define STAGE_A_GLL(k0, bi)                                                      \
    GLL16((const u16*)Xv + (r0 + arow) * 256 + (k0) + aseg * 8,                  \
          sA + (bi) * 2048 + wave * 512);

    {   // prologue: stage tile 0 into buf 0
        if (XBF) { STAGE_A_GLL(0, 0) }
        else { uint4 aC; LOAD_A_F32(0, aC) *(uint4*)(sA + tid * 8) = aC; }
        STAGE_B_GLL(0, 0)
    }

    for (int k = 0; k < 8; ++k) {
        const int cur = k & 1;
        __syncthreads();                 // drains GLL vmcnt + lgkm; frees buf^1
        uint4 aN;
        if (k < 7) {
            const int k0n = (k + 1) * 32;
            if (XBF) { STAGE_A_GLL(k0n, cur ^ 1) }
            else     { LOAD_A_F32(k0n, aN) }
            STAGE_B_GLL(k0n, cur ^ 1)
        }
        const u16* A  = sA + cur * 2048;
        const u16* Bb = sB + cur * 8192;
        bf16x8 a[4], b[4];
#pragma unroll
        for (int f = 0; f < 4; ++f)
            a[f] = *(const bf16x8*)(A + (f * 16 + rbase) * 32 + kseg);
#pragma unroll
        for (int f = 0; f < 4; ++f)
            b[f] = *(const bf16x8*)(Bb + (wave * 64 + f * 16 + rbase) * 32 + kseg);
#pragma unroll
        for (int rf = 0; rf < 4; ++rf)
#pragma unroll
            for (int cf = 0; cf < 4; ++cf)
                acc[rf][cf] = __builtin_amdgcn_mfma_f32_16x16x32_bf16(
                    a[rf], b[cf], acc[rf][cf], 0, 0, 0);
        if (k < 7 && !XBF)
            *(uint4*)(sA + (cur ^ 1) * 2048 + tid * 8) = aN;
    }
#undef LOAD_A_F32
#undef STAGE_B_GLL
#undef STAGE_A_GLL

    // C/D mapping (bit-verified vs VALU GEMM rounds 2/3): col=lane&15, row=(lane>>4)*4+reg
    const int orow = (lane >> 4) * 4, ocol = lane & 15;
    if (OUTF32) {
#pragma unroll
        for (int cf = 0; cf < 4; ++cf) {
            const int col = wave * 64 + cf * 16 + ocol;
            const float bv = bias[col];
#pragma unroll
            for (int rf = 0; rf < 4; ++rf)
#pragma unroll
                for (int r = 0; r < 4; ++r)
                    ((float*)Yv)[(r0 + rf * 16 + orow + r) * 256 + col] =
                        acc[rf][cf][r] + bv;
        }
    } else {
        // bf16 out: LDS transpose (reuse dead staging LDS) -> coalesced dwordx4
        __syncthreads();                 // all ds_reads of last tile done
#pragma unroll
        for (int cf = 0; cf < 4; ++cf) {
            const int col = wave * 64 + cf * 16 + ocol;
            const float bv = bias[col];
#pragma unroll
            for (int rf = 0; rf < 4; ++rf)
#pragma unroll
                for (int r = 0; r < 4; ++r)
                    smem[(rf * 16 + orow + r) * 256 + col] = f2b(acc[rf][cf][r] + bv);
        }
        __syncthreads();
#pragma unroll
        for (int i = 0; i < 8; ++i) {
            const int s = i * 256 + tid;
            *(uint4*)((u16*)Yv + r0 * 256 + (size_t)s * 8) = *(const uint4*)(smem + s * 8);
        }
    }
}

template<int XBF, int OUTF32>
__global__ __launch_bounds__(256) void k_gemm_m(const void* __restrict__ Xv,
                                                const u16* __restrict__ Wb,
                                                const float* __restrict__ bias,
                                                void* __restrict__ Yv)
{
    __shared__ __align__(16) u16 smem[20480];
    gemm_body<XBF, OUTF32>(Xv, Wb, bias, Yv, blockIdx.x, smem);
}

// Fused 3-projection GEMM: blockIdx.y selects {q,k,v}; Wb = pre-converted bf16.
__global__ __launch_bounds__(256) void k_gemm_qkv(
    const float* __restrict__ X0, const float* __restrict__ X1, const float* __restrict__ X2,
    const u16* __restrict__ Wb,
    const float* __restrict__ b0, const float* __restrict__ b1, const float* __restrict__ b2,
    u16* __restrict__ Y0, u16* __restrict__ Y1, u16* __restrict__ Y2)
{
    __shared__ __align__(16) u16 smem[20480];
    const int sel = blockIdx.y;
    const float* X = sel == 0 ? X0 : sel == 1 ? X1 : X2;
    const float* bb = sel == 0 ? b0 : sel == 1 ? b1 : b2;
    u16* Y = sel == 0 ? Y0 : sel == 1 ? Y1 : Y2;
    gemm_body<0, 0>(X, Wb + sel * 65536, bb, Y, blockIdx.x, smem);
}

// ---------------- temporal attention (MFMA): one block per (t-pair, b) --------
__global__ __launch_bounds__(256) void k_attn_t(
    const u16* __restrict__ Qt, const u16* __restrict__ Kt, const u16* __restrict__ Vt,
    const u16* __restrict__ Ks, const u16* __restrict__ Vs,
    const int* __restrict__ maskT, const int* __restrict__ maskS,
    float* __restrict__ tw, u16* __restrict__ qkvt)
{
    const int tp = blockIdx.x, b = blockIdx.y;
    const int t0 = tp * 2;
    __shared__ __align__(16) u16 sQ [4 * 2 * 16 * 32];   // [h][ks][row16][32]
    __shared__ __align__(16) u16 sKT[4 * 2 * 16 * 32];
    __shared__ __align__(16) u16 sKS[4 * 2 * 32 * 32];
    __shared__ __align__(16) u16 sVT[4 * 64 * 72];       // [h][d64][key72], keys48-63=0
    __shared__ __align__(16) u16 sP [4 * 16 * 72];
    __shared__ int smT[2][8];
    __shared__ int smS[32];
    const int tid = threadIdx.x;

#pragma unroll
    for (int i = 0; i < 2; ++i) {
        const int fl = tid + i * 256;
        const int r = fl >> 5, c32 = fl & 31;
        const int h = c32 >> 3, ks = (c32 >> 2) & 1, seg = c32 & 3;
        const size_t src = (((size_t)b * T_ + t0 + (r >> 3)) * 8 + (r & 7)) * 256 + c32 * 8;
        const int dst = h * 1024 + ks * 512 + r * 32 + seg * 8;
        *(uint4*)(sQ  + dst) = *(const uint4*)(Qt + src);
        *(uint4*)(sKT + dst) = *(const uint4*)(Kt + src);
    }
#pragma unroll
    for (int i = 0; i < 4; ++i) {
        const int fl = tid + i * 256;
        const int r = fl >> 5, c32 = fl & 31;
        const int h = c32 >> 3, ks = (c32 >> 2) & 1, seg = c32 & 3;
        *(uint4*)(sKS + h * 2048 + ks * 1024 + r * 32 + seg * 8) =
            *(const uint4*)(Ks + ((size_t)b * S_ + r) * 256 + c32 * 8);
    }
    {
        const int key = tid & 63, dg = tid >> 6;
        const u16* vrow = nullptr;
        if (key < 16)      vrow = Vt + (((size_t)b * T_ + t0 + (key >> 3)) * 8 + (key & 7)) * 256;
        else if (key < 48) vrow = Vs + ((size_t)b * S_ + (key - 16)) * 256;
#pragma unroll
        for (int i = 0; i < 8; ++i) {
            const int dseg = dg * 8 + i;
            uint4 v = {0, 0, 0, 0};
            if (vrow) v = *(const uint4*)(vrow + dseg * 8);
            const int h = dseg >> 3, dl0 = (dseg & 7) * 8;
            const u16* pv = (const u16*)&v;
#pragma unroll
            for (int j = 0; j < 8; ++j)
                sVT[h * 4608 + (dl0 + j) * 72 + key] = pv[j];
        }
    }
    if (tid < 16) smT[tid >> 3][tid & 7] =
        maskT[((size_t)b * T_ + t0 + (tid >> 3)) * 8 + (tid & 7)];
    if (tid < 32) smS[tid] = maskS[b * S_ + tid];
    __syncthreads();

    const int h = tid >> 6, lane = tid & 63;
    const int c = lane & 15, g = lane >> 4, th = g >> 1;

    f32x4 at = {0,0,0,0}, as0 = {0,0,0,0}, as1 = {0,0,0,0};
#pragma unroll
    for (int ks = 0; ks < 2; ++ks) {
        bf16x8 aq = *(const bf16x8*)(sQ  + h * 1024 + ks * 512 + c * 32 + g * 8);
        bf16x8 bt = *(const bf16x8*)(sKT + h * 1024 + ks * 512 + c * 32 + g * 8);
        bf16x8 b0 = *(const bf16x8*)(sKS + h * 2048 + ks * 1024 + c * 32 + g * 8);
        bf16x8 b1 = *(const bf16x8*)(sKS + h * 2048 + ks * 1024 + 512 + c * 32 + g * 8);
        at  = __builtin_amdgcn_mfma_f32_16x16x32_bf16(aq, bt, at, 0, 0, 0);
        as0 = __builtin_amdgcn_mfma_f32_16x16x32_bf16(aq, b0, as0, 0, 0, 0);
        as1 = __builtin_amdgcn_mfma_f32_16x16x32_bf16(aq, b1, as1, 0, 0, 0);
    }

    const int vt = ((c >> 3) == th) ? smT[th][c & 7] : 0;
    const int v0 = smS[c], v1 = smS[16 + c];
    float st[4], s0[4], s1[4], mx[4];
#pragma unroll
    for (int r = 0; r < 4; ++r) {
        st[r] = vt ? at[r]  * 0.125f : -1e30f;
        s0[r] = v0 ? as0[r] * 0.125f : -1e30f;
        s1[r] = v1 ? as1[r] * 0.125f : -1e30f;
        mx[r] = fmaxf(fmaxf(st[r], s0[r]), s1[r]);
    }
#pragma unroll
    for (int o = 1; o < 16; o <<= 1)
#pragma unroll
        for (int r = 0; r < 4; ++r) mx[r] = fmaxf(mx[r], __shfl_xor(mx[r], o));
    float pt[4], p0[4], p1[4], sum[4];
#pragma unroll
    for (int r = 0; r < 4; ++r) {
        pt[r] = __expf(st[r] - mx[r]);
        p0[r] = __expf(s0[r] - mx[r]);
        p1[r] = __expf(s1[r] - mx[r]);
        sum[r] = pt[r] + p0[r] + p1[r];
    }
#pragma unroll
    for (int o = 1; o < 16; o <<= 1)
#pragma unroll
        for (int r = 0; r < 4; ++r) sum[r] += __shfl_xor(sum[r], o);
#pragma unroll
    for (int r = 0; r < 4; ++r) {
        const float inv = 1.0f / sum[r];
        pt[r] *= inv; p0[r] *= inv; p1[r] *= inv;
    }

#pragma unroll
    for (int r = 0; r < 4; ++r) {
        const int row = g * 4 + r;
        const int tt = t0 + (row >> 3), m = row & 7;
        float* twp = tw + ((((size_t)b * H_ + h) * T_ + tt) * 8 + m) * NKT;
        if ((c >> 3) == th) twp[c & 7] = pt[r];
        twp[8 + c]  = p0[r];
        twp[24 + c] = p1[r];
        u16* sp = sP + h * 1152 + row * 72;
        sp[c]      = f2b(pt[r]);
        sp[16 + c] = f2b(p0[r]);
        sp[32 + c] = f2b(p1[r]);
        sp[48 + c] = 0;
    }

    f32x4 o4[4] = {{0,0,0,0}, {0,0,0,0}, {0,0,0,0}, {0,0,0,0}};
#pragma unroll
    for (int ks = 0; ks < 2; ++ks) {
        bf16x8 pa = *(const bf16x8*)(sP + h * 1152 + c * 72 + ks * 32 + g * 8);
#pragma unroll
        for (int dt = 0; dt < 4; ++dt) {
            bf16x8 pb = *(const bf16x8*)(sVT + h * 4608 + (dt * 16 + c) * 72 + ks * 32 + g * 8);
            o4[dt] = __builtin_amdgcn_mfma_f32_16x16x32_bf16(pa, pb, o4[dt], 0, 0, 0);
        }
    }
#pragma unroll
    for (int dt = 0; dt < 4; ++dt)
#pragma unroll
        for (int r = 0; r < 4; ++r) {
            const int row = g * 4 + r;
            const int tt = t0 + (row >> 3), m = row & 7;
            qkvt[(((size_t)b * T_ + tt) * 8 + m) * 256 + h * 64 + dt * 16 + c] = f2b(o4[dt][r]);
        }
}

// ---------------- static branch: raw masked scores (MFMA) ----------------
__global__ __launch_bounds__(256) void k_attn_s_scores(
    const u16* __restrict__ Qs, const u16* __restrict__ Kt, const u16* __restrict__ Ks,
    const int* __restrict__ maskT, const int* __restrict__ maskS,
    float* __restrict__ raw)
{
    const int ch = blockIdx.x, h = blockIdx.y, b = blockIdx.z;
    const int nk = (ch < 32) ? 128 : 32;
    const int k0 = ch * 128;
    __shared__ __align__(16) u16 sQ[2 * 32 * 32];
    __shared__ __align__(16) u16 sK[2 * 128 * 32];
    __shared__ int sM[128];
    const int tid = threadIdx.x;

    {   const int q = tid >> 3, c8 = tid & 7;
        const int ks = c8 >> 2, seg = c8 & 3;
        *(uint4*)(sQ + ks * 1024 + q * 32 + seg * 8) =
            *(const uint4*)(Qs + ((size_t)b * S_ + q) * 256 + h * 64 + c8 * 8);
    }
#pragma unroll
    for (int i = 0; i < 4; ++i) {
        const int fl = tid + i * 256;
        const int key = fl >> 3, c8 = fl & 7;
        const int ks = c8 >> 2, seg = c8 & 3;
        if (key < nk) {
            const u16* src = (ch < 32)
                ? (Kt + ((size_t)b * TM_ + k0 + key) * 256 + h * 64 + c8 * 8)
                : (Ks + ((size_t)b * S_  +      key) * 256 + h * 64 + c8 * 8);
            *(uint4*)(sK + ks * 4096 + key * 32 + seg * 8) = *(const uint4*)src;
        }
    }
    if (tid < nk) sM[tid] = (ch < 32) ? maskT[(size_t)b * TM_ + k0 + tid]
                                      : maskS[b * S_ + tid];
    __syncthreads();

    const int w = tid >> 6, lane = tid & 63;
    if (w * 32 >= nk) return;
    const int c = lane & 15, g = lane >> 4;

    f32x4 acc[2][2] = {{{0,0,0,0}, {0,0,0,0}}, {{0,0,0,0}, {0,0,0,0}}};
#pragma unroll
    for (int ks = 0; ks < 2; ++ks) {
        bf16x8 a0 = *(const bf16x8*)(sQ + ks * 1024 +        c * 32 + g * 8);
        bf16x8 a1 = *(const bf16x8*)(sQ + ks * 1024 + 512 +  c * 32 + g * 8);
        bf16x8 b0 = *(const bf16x8*)(sK + ks * 4096 + (w * 32 +      c) * 32 + g * 8);
        bf16x8 b1 = *(const bf16x8*)(sK + ks * 4096 + (w * 32 + 16 + c) * 32 + g * 8);
        acc[0][0] = __builtin_amdgcn_mfma_f32_16x16x32_bf16(a0, b0, acc[0][0], 0, 0, 0);
        acc[0][1] = __builtin_amdgcn_mfma_f32_16x16x32_bf16(a0, b1, acc[0][1], 0, 0, 0);
        acc[1][0] = __builtin_amdgcn_mfma_f32_16x16x32_bf16(a1, b0, acc[1][0], 0, 0, 0);
        acc[1][1] = __builtin_amdgcn_mfma_f32_16x16x32_bf16(a1, b1, acc[1][1], 0, 0, 0);
    }
#pragma unroll
    for (int rt = 0; rt < 2; ++rt)
#pragma unroll
        for (int ct = 0; ct < 2; ++ct) {
            const int kl = w * 32 + ct * 16 + c;
            const float madd = sM[kl] ? 0.f : -1e30f;
#pragma unroll
            for (int r = 0; r < 4; ++r) {
                const int q = rt * 16 + g * 4 + r;
                raw[(((size_t)b * H_ + h) * S_ + q) * NKS + k0 + kl] =
                    acc[rt][ct][r] * 0.125f + madd;
            }
        }
}

// ---------------- static branch: row softmax (reads raw, writes sw only) -------
__global__ __launch_bounds__(256) void k_attn_s_softmax(
    const float* __restrict__ raw, float* __restrict__ sw)
{
    const int q = blockIdx.x, h = blockIdx.y, b = blockIdx.z;
    __shared__ float sRow[NKS];
    __shared__ float red[8];
    const int tid = threadIdx.x;
    const size_t base = (((size_t)b * H_ + h) * S_ + q) * NKS;

    float mx = -1e30f;
    for (int i = tid; i < NKS; i += 256) {
        const float v = raw[base + i];
        sRow[i] = v;
        mx = fmaxf(mx, v);
    }
    for (int o = 32; o; o >>= 1) mx = fmaxf(mx, __shfl_xor(mx, o));
    if ((tid & 63) == 0) red[tid >> 6] = mx;
    __syncthreads();
    mx = fmaxf(fmaxf(red[0], red[1]), fmaxf(red[2], red[3]));

    float sum = 0.f;
    for (int i = tid; i < NKS; i += 256) {
        const float e = __expf(sRow[i] - mx);
        sRow[i] = e;
        sum += e;
    }
    for (int o = 32; o; o >>= 1) sum += __shfl_xor(sum, o);
    if ((tid & 63) == 0) red[4 + (tid >> 6)] = sum;
    __syncthreads();
    sum = (red[4] + red[5]) + (red[6] + red[7]);
    const float inv = 1.0f / sum;

    for (int i = tid; i < NKS; i += 256)
        sw[base + i] = sRow[i] * inv;           // single copy; pv reads sw
}

// ---------------- static branch: split-K PV partials (reads sw) ----------------
__global__ __launch_bounds__(256) void k_attn_s_pv_part(
    const float* __restrict__ w, const u16* __restrict__ Vt, const u16* __restrict__ Vs,
    float* __restrict__ part)
{
    const int ch = blockIdx.x, h = blockIdx.y, b = blockIdx.z;
    const int nk = (ch < 32) ? 128 : 32;
    const int k0 = ch * 128;
    __shared__ float sW[32][132];
    __shared__ __align__(16) u16 sV[128 * 64];
    const int tid = threadIdx.x;

#pragma unroll
    for (int i = 0; i < 4; ++i) {
        const int fl = tid + i * 256;
        const int q = fl >> 5, k4 = fl & 31;
        if (k4 * 4 < nk)
            *(float4*)&sW[q][k4 * 4] =
                *(const float4*)(w + (((size_t)b * H_ + h) * S_ + q) * NKS + k0 + k4 * 4);
    }
#pragma unroll
    for (int i = 0; i < 4; ++i) {
        const int fl = tid + i * 256;
        const int key = fl >> 3, pp = fl & 7;
        if (key < nk) {
            const u16* src = (ch < 32)
                ? (Vt + ((size_t)b * TM_ + k0 + key) * D_ + h * HD_ + pp * 8)
                : (Vs + ((size_t)b * S_  +      key) * D_ + h * HD_ + pp * 8);
            ((uint4*)sV)[fl] = *(const uint4*)src;
        }
    }
    __syncthreads();

    const int d = tid & 63, qg = tid >> 6;
    float acc[8] = {0,0,0,0,0,0,0,0};
    for (int kk = 0; kk < nk; kk += 4) {
        const float v0 = b2f(sV[(kk + 0) * 64 + d]);
        const float v1 = b2f(sV[(kk + 1) * 64 + d]);
        const float v2 = b2f(sV[(kk + 2) * 64 + d]);
        const float v3 = b2f(sV[(kk + 3) * 64 + d]);
#pragma unroll
        for (int j = 0; j < 8; ++j) {
            const float4 wv = *(const float4*)&sW[qg * 8 + j][kk];
            acc[j] += wv.x * v0 + wv.y * v1 + wv.z * v2 + wv.w * v3;
        }
    }

    float* pb = part + (((size_t)ch * B_ + b) * H_ + h) * 2048;
#pragma unroll
    for (int j = 0; j < 8; ++j)
        pb[(qg * 8 + j) * 64 + d] = acc[j];
}

// ---------------- static branch: PV reduce ----------------
__global__ __launch_bounds__(256) void k_attn_s_pv_red(
    const float* __restrict__ part, u16* __restrict__ qkvs)
{
    const int h = blockIdx.x, b = blockIdx.y;
    const int tid = threadIdx.x;
    for (int i = tid; i < 2048; i += 256) {
        float s = 0.f;
#pragma unroll
        for (int c = 0; c < 33; ++c)
            s += part[(((size_t)c * B_ + b) * H_ + h) * 2048 + i];
        const int q = i >> 6, d = i & 63;
        qkvs[((size_t)b * S_ + q) * D_ + h * HD_ + d] = f2b(s);
    }
}

// ---------------- launch ----------------
extern "C" void kernel_launch(void* const* d_in, const int* in_sizes, int n_in,
                              void* d_out, int out_size, void* d_ws, size_t ws_size,
                              hipStream_t stream)
{
    const float* q_t = (const float*)d_in[0];
    const float* q_s = (const float*)d_in[1];
    const float* k_t = (const float*)d_in[2];
    const float* v_t = (const float*)d_in[3];
    const float* k_s = (const float*)d_in[4];
    const float* v_s = (const float*)d_in[5];
    const float* q_w = (const float*)d_in[6];
    const float* q_b = (const float*)d_in[7];
    const float* k_w = (const float*)d_in[8];
    const float* k_b = (const float*)d_in[9];
    const float* v_w = (const float*)d_in[10];
    const float* v_b = (const float*)d_in[11];
    const float* o_w = (const float*)d_in[12];
    const float* o_b = (const float*)d_in[13];
    const int* maskT = (const int*)d_in[14];
    // d_in[15] = mask_fcst: unused by the reference
    const int* maskS = (const int*)d_in[16];
    float* out = (float*)d_out;

    char* ws = (char*)d_ws;
    u16*   Kt   = (u16*)(ws + 0);
    u16*   Vt   = (u16*)(ws + 33554432);
    u16*   QKVt = (u16*)(ws + 67108864);
    float* part = (float*)(ws + 67108864);   // aliases QKVt (dead after out_t GEMM)
    u16*   Wqkv = (u16*)(ws + 67108864);     // aliases QKVt: live only during qkv GEMMs
    u16*   Qs   = (u16*)(ws + 100663296);
    u16*   Ks   = (u16*)(ws + 100925440);
    u16*   Vs   = (u16*)(ws + 101187584);
    u16*   QKVs = (u16*)(ws + 101449728);
    u16*   Qt   = (u16*)(ws + 101711872);
    float* raw  = (float*)(ws + 101711872);  // aliases Qt (dead before scores run)
    u16*   Wo   = (u16*)(ws + 101711872);    // aliases raw head: converted twice (see order)
    if (ws_size < 135528448) return;         // required workspace

    float* out_t = out;                 // [B,T,M,D]
    float* out_s = out + 16777216;      // [B,S,D]
    float* tw    = out + 16908288;      // [B,H,T,M,40]
    float* sw    = out + 27394048;      // [B,H,S,4128]

    const dim3 blk(256);
    // W pre-convert (q,k,v) into dead QKVt region
    k_cvt_w<<<dim3(32, 3), blk, 0, stream>>>(q_w, k_w, v_w, Wqkv);

    k_gemm_qkv<<<dim3(1024, 3), blk, 0, stream>>>(q_t, k_t, v_t, Wqkv,
                                                  q_b, k_b, v_b, Qt, Kt, Vt);
    k_gemm_qkv<<<dim3(8, 3),    blk, 0, stream>>>(q_s, k_s, v_s, Wqkv,
                                                  q_b, k_b, v_b, Qs, Ks, Vs);

    k_attn_t<<<dim3(256, 16), blk, 0, stream>>>(Qt, Kt, Vt, Ks, Vs, maskT, maskS, tw, QKVt);

    // o_w convert #1 into raw region (Qt dead after attn_t; scores clobbers it later)
    k_cvt_w<<<dim3(32, 1), blk, 0, stream>>>(o_w, o_w, o_w, Wo);
    // out_t projection: frees QKVt so PV partials can alias it.
    k_gemm_m<1,1><<<dim3(1024), blk, 0, stream>>>(QKVt, Wo, o_b, out_t);

    k_attn_s_scores<<<dim3(33, 4, 16), blk, 0, stream>>>(Qs, Kt, Ks, maskT, maskS, raw);
    k_attn_s_softmax<<<dim3(32, 4, 16), blk, 0, stream>>>(raw, sw);
    // o_w convert #2 (raw dead after softmax; pv reads sw)
    k_cvt_w<<<dim3(32, 1), blk, 0, stream>>>(o_w, o_w, o_w, Wo);
    k_attn_s_pv_part<<<dim3(33, 4, 16), blk, 0, stream>>>(sw, Vt, Vs, part);
    k_attn_s_pv_red<<<dim3(4, 16), blk, 0, stream>>>(part, QKVs);

    k_gemm_m<1,1><<<dim3(8),    blk, 0, stream>>>(QKVs, Wo, o_b, out_s);
}